// Round 11
// baseline (323.788 us; speedup 1.0000x reference)
//
#include <hip/hip_runtime.h>
#include <math.h>

#define F_IN  512
#define F_HID 256
#define F_OUT 64

typedef __attribute__((ext_vector_type(8))) short bf16x8;
typedef __attribute__((ext_vector_type(4))) float f32x4;

__device__ __forceinline__ ushort f2bf(float f) {
    union { float f; uint32_t u; } v; v.f = f;
    uint32_t r = (v.u + 0x7FFFu + ((v.u >> 16) & 1u)) >> 16;
    return (ushort)r;
}

__device__ __forceinline__ float bf2f(ushort u) {
    union { uint32_t u; float f; } v; v.u = ((uint32_t)u) << 16;
    return v.f;
}

__device__ __forceinline__ bf16x8 conv8(float4 a, float4 b) {
    bf16x8 c;
    c[0] = (short)f2bf(a.x); c[1] = (short)f2bf(a.y);
    c[2] = (short)f2bf(a.z); c[3] = (short)f2bf(a.w);
    c[4] = (short)f2bf(b.x); c[5] = (short)f2bf(b.y);
    c[6] = (short)f2bf(b.z); c[7] = (short)f2bf(b.w);
    return c;
}

// ---------------- degree ----------------
__global__ void k_deg(const int* __restrict__ dst, int* __restrict__ deg, int E) {
    int e = blockIdx.x * 256 + threadIdx.x;
    if (e < E) atomicAdd(&deg[dst[e]], 1);
}

// ---------------- scan level 1 (+ dinv fused) ----------------
__global__ void k_scan1(const int* __restrict__ deg, int* __restrict__ offs,
                        int* __restrict__ bsums, float* __restrict__ dinv, int N) {
    __shared__ int s[256];
    int tid = threadIdx.x;
    int i = blockIdx.x * 256 + tid;
    int v = (i < N) ? deg[i] : 0;
    if (i < N) dinv[i] = rsqrtf((float)(v + 1));   // +1 self loop
    s[tid] = v; __syncthreads();
    for (int d = 1; d < 256; d <<= 1) {
        int t = (tid >= d) ? s[tid - d] : 0;
        __syncthreads();
        s[tid] += t;
        __syncthreads();
    }
    if (i < N) offs[i] = s[tid] - v;
    if (tid == 255) bsums[blockIdx.x] = s[255];
}

__global__ void k_scan2(int* __restrict__ bsums, int n) {
    __shared__ int s[256];
    int tid = threadIdx.x;
    int v = (tid < n) ? bsums[tid] : 0;
    s[tid] = v; __syncthreads();
    for (int d = 1; d < 256; d <<= 1) {
        int t = (tid >= d) ? s[tid - d] : 0;
        __syncthreads();
        s[tid] += t;
        __syncthreads();
    }
    if (tid < n) bsums[tid] = s[tid] - v;
}

__global__ void k_scan3(int* __restrict__ offs, const int* __restrict__ bsums,
                        int* __restrict__ cursor, int2* __restrict__ jw, int N, int E) {
    int i = blockIdx.x * 256 + threadIdx.x;
    if (i < N) {
        int o = offs[i] + bsums[i >> 8];
        offs[i] = o;
        cursor[i] = o;
    }
    if (i == 0) offs[N] = E;
    if (i < 16) jw[E + i] = make_int2(0, 0);   // pad: row 0, weight 0
}

// fill packed (src_index, dinv[src]) per CSR slot
__global__ void k_fill(const int* __restrict__ src, const int* __restrict__ dst,
                       int* __restrict__ cursor, int2* __restrict__ jw,
                       const float* __restrict__ dinv, int E) {
    int e = blockIdx.x * 256 + threadIdx.x;
    if (e < E) {
        int s = src[e];
        int pos = atomicAdd(&cursor[dst[e]], 1);
        jw[pos] = make_int2(s, __float_as_int(dinv[s]));
    }
}

// ---------------- weight transpose-casts (W1 and W2 in one launch) ----------------
__global__ void k_tcast2(const float* __restrict__ W1, ushort* __restrict__ w1t,
                         const float* __restrict__ W2, ushort* __restrict__ w2t) {
    int idx = blockIdx.x * 256 + threadIdx.x;
    const int n1 = F_IN * F_HID;
    if (idx < n1) {
        int n = idx / F_IN, k = idx - n * F_IN;
        w1t[idx] = f2bf(W1[(size_t)k * F_HID + n]);
    } else {
        int t = idx - n1;
        if (t < F_HID * F_OUT) {
            int n = t / F_HID, k = t - n * F_HID;
            w2t[t] = f2bf(W2[(size_t)k * F_OUT + n]);
        }
    }
}

// ---------------- GEMM1 (no-LDS): h1[M,256] = bf16( fp32 x[M,512] @ w1t^T ) ----------------
// BM=64 x BN=128, 4 waves 2x2, zero LDS / zero barriers. A: per-lane coalesced
// fp32 loads + in-reg convert. B: per-lane bf16x8 loads, L2-resident (w1t=256KB).
// Compiler pipelines freely (no vmcnt(0) drain); occupancy VGPR-bound only.
__global__ __launch_bounds__(256) void k_gemm1(
        const float* __restrict__ A, const ushort* __restrict__ Bt,
        ushort* __restrict__ C, int M) {
    constexpr int K = F_IN, Nc = F_HID, BM = 64, NT = K / 32;
    const int tid  = threadIdx.x;
    const int wave = tid >> 6, lane = tid & 63;
    const int wr = wave & 1, wc = wave >> 1;
    const int brow = blockIdx.y * BM, bcol = blockIdx.x * 128;

    const int l15 = lane & 15;
    const int kq  = (lane >> 4) * 8;

    int r0 = brow + wr * 32 + l15; if (r0 >= M) r0 = M - 1;
    int r1 = r0 + 16;              if (r1 >= M) r1 = M - 1;
    const float* a0p = &A[(size_t)r0 * K + kq];
    const float* a1p = &A[(size_t)r1 * K + kq];
    const ushort* bp0 = &Bt[(size_t)(bcol + wc * 64 + l15) * K + kq];

    f32x4 acc[2][4];
    #pragma unroll
    for (int m = 0; m < 2; ++m)
        #pragma unroll
        for (int n = 0; n < 4; ++n) acc[m][n] = (f32x4){0.f, 0.f, 0.f, 0.f};

    #pragma unroll 4
    for (int t = 0; t < NT; ++t) {
        const int ko = t * 32;
        float4 x00 = *(const float4*)(a0p + ko);
        float4 x01 = *(const float4*)(a0p + ko + 4);
        float4 x10 = *(const float4*)(a1p + ko);
        float4 x11 = *(const float4*)(a1p + ko + 4);
        bf16x8 bfr[4];
        #pragma unroll
        for (int n = 0; n < 4; ++n)
            bfr[n] = *(const bf16x8*)(bp0 + (size_t)n * 16 * K + ko);
        bf16x8 af0 = conv8(x00, x01);
        bf16x8 af1 = conv8(x10, x11);
        #pragma unroll
        for (int n = 0; n < 4; ++n) {
            acc[0][n] = __builtin_amdgcn_mfma_f32_16x16x32_bf16(af0, bfr[n], acc[0][n], 0, 0, 0);
            acc[1][n] = __builtin_amdgcn_mfma_f32_16x16x32_bf16(af1, bfr[n], acc[1][n], 0, 0, 0);
        }
    }

    const int crow0 = brow + wr * 32 + (lane >> 4) * 4;
    const int ccol0 = bcol + wc * 64 + l15;
    #pragma unroll
    for (int m = 0; m < 2; ++m)
        #pragma unroll
        for (int n = 0; n < 4; ++n)
            #pragma unroll
            for (int j = 0; j < 4; ++j) {
                int row = crow0 + m * 16 + j;
                if (row < M) C[(size_t)row * Nc + ccol0 + n * 16] = f2bf(acc[m][n][j]);
            }
}

// ---------------- GEMM2 (no-LDS): h2[M,64] = bf16( a1[M,256] @ w2t^T ) ----------------
// BM=64 x BN=64 (full width), 4 waves 2x2. A bf16 direct loads; B L2-resident (32KB).
__global__ __launch_bounds__(256) void k_gemm2(
        const ushort* __restrict__ A, const ushort* __restrict__ Bt,
        ushort* __restrict__ C, int M) {
    constexpr int K = F_HID, Nc = F_OUT, BM = 64, NT = K / 32;
    const int tid  = threadIdx.x;
    const int wave = tid >> 6, lane = tid & 63;
    const int wr = wave & 1, wc = wave >> 1;
    const int brow = blockIdx.y * BM;

    const int l15 = lane & 15;
    const int kq  = (lane >> 4) * 8;

    int r0 = brow + wr * 32 + l15; if (r0 >= M) r0 = M - 1;
    int r1 = r0 + 16;              if (r1 >= M) r1 = M - 1;
    const ushort* a0p = &A[(size_t)r0 * K + kq];
    const ushort* a1p = &A[(size_t)r1 * K + kq];
    const ushort* bp0 = &Bt[(size_t)(wc * 32 + l15) * K + kq];

    f32x4 acc[2][2];
    #pragma unroll
    for (int m = 0; m < 2; ++m)
        #pragma unroll
        for (int n = 0; n < 2; ++n) acc[m][n] = (f32x4){0.f, 0.f, 0.f, 0.f};

    #pragma unroll
    for (int t = 0; t < NT; ++t) {
        const int ko = t * 32;
        bf16x8 af0 = *(const bf16x8*)(a0p + ko);
        bf16x8 af1 = *(const bf16x8*)(a1p + ko);
        bf16x8 b0  = *(const bf16x8*)(bp0 + ko);
        bf16x8 b1  = *(const bf16x8*)(bp0 + (size_t)16 * K + ko);
        acc[0][0] = __builtin_amdgcn_mfma_f32_16x16x32_bf16(af0, b0, acc[0][0], 0, 0, 0);
        acc[0][1] = __builtin_amdgcn_mfma_f32_16x16x32_bf16(af0, b1, acc[0][1], 0, 0, 0);
        acc[1][0] = __builtin_amdgcn_mfma_f32_16x16x32_bf16(af1, b0, acc[1][0], 0, 0, 0);
        acc[1][1] = __builtin_amdgcn_mfma_f32_16x16x32_bf16(af1, b1, acc[1][1], 0, 0, 0);
    }

    const int crow0 = brow + wr * 32 + (lane >> 4) * 4;
    const int ccol0 = wc * 32 + l15;
    #pragma unroll
    for (int m = 0; m < 2; ++m)
        #pragma unroll
        for (int n = 0; n < 2; ++n)
            #pragma unroll
            for (int j = 0; j < 4; ++j) {
                int row = crow0 + m * 16 + j;
                if (row < M) C[(size_t)row * Nc + ccol0 + n * 16] = f2bf(acc[m][n][j]);
            }
}

// ---------------- layer-1 aggregation: paired-row gathers ----------------
__global__ __launch_bounds__(256) void k_agg1(
        const ushort* __restrict__ h, const int2* __restrict__ jw,
        const int* __restrict__ offs, const float* __restrict__ dinv,
        const float* __restrict__ bias, ushort* __restrict__ outm, int N) {
    int wave = threadIdx.x >> 6, lane = threadIdx.x & 63;
    int i = blockIdx.x * 4 + wave;
    if (i >= N) return;
    int g = lane & 31;        // features g*8 .. g*8+7
    int p = lane >> 5;        // edge parity
    float di = dinv[i];
    float acc[8];
    {
        bf16x8 hv = *(const bf16x8*)&h[(size_t)i * F_HID + g * 8];
        float w = (p == 0) ? di * di : 0.f;     // self loop counted once
        #pragma unroll
        for (int k = 0; k < 8; ++k) acc[k] = bf2f((ushort)hv[k]) * w;
    }
    int s = offs[i], e = offs[i + 1];
    for (int u = s; u < e; u += 12) {
        int2 a[6];
        #pragma unroll
        for (int q = 0; q < 6; ++q) a[q] = jw[u + 2 * q + p];   // overrun -> pad/next-node, masked
        bf16x8 hv[6];
        #pragma unroll
        for (int q = 0; q < 6; ++q)
            hv[q] = *(const bf16x8*)&h[(size_t)a[q].x * F_HID + g * 8];
        #pragma unroll
        for (int q = 0; q < 6; ++q) {
            float ww = (u + 2 * q + p < e) ? __int_as_float(a[q].y) * di : 0.f;
            #pragma unroll
            for (int k = 0; k < 8; ++k) acc[k] += bf2f((ushort)hv[q][k]) * ww;
        }
    }
    #pragma unroll
    for (int k = 0; k < 8; ++k) acc[k] += __shfl_xor(acc[k], 32, 64);
    if (p == 0) {
        float4 b0 = *(const float4*)&bias[g * 8];
        float4 b1 = *(const float4*)&bias[g * 8 + 4];
        bf16x8 o;
        o[0] = (short)f2bf(fmaxf(acc[0] + b0.x, 0.f));
        o[1] = (short)f2bf(fmaxf(acc[1] + b0.y, 0.f));
        o[2] = (short)f2bf(fmaxf(acc[2] + b0.z, 0.f));
        o[3] = (short)f2bf(fmaxf(acc[3] + b0.w, 0.f));
        o[4] = (short)f2bf(fmaxf(acc[4] + b1.x, 0.f));
        o[5] = (short)f2bf(fmaxf(acc[5] + b1.y, 0.f));
        o[6] = (short)f2bf(fmaxf(acc[6] + b1.z, 0.f));
        o[7] = (short)f2bf(fmaxf(acc[7] + b1.w, 0.f));
        *(bf16x8*)&outm[(size_t)i * F_HID + g * 8] = o;
    }
}

// ---------------- layer-2 aggregation + bias + log_softmax: wave per node, 8-unroll ----------------
__global__ __launch_bounds__(256) void k_agg2(
        const ushort* __restrict__ h, const int2* __restrict__ jw,
        const int* __restrict__ offs, const float* __restrict__ dinv,
        const float* __restrict__ bias, float* __restrict__ outm, int N) {
    int wave = threadIdx.x >> 6, lane = threadIdx.x & 63;
    int i = blockIdx.x * 4 + wave;
    if (i >= N) return;
    float di = dinv[i];
    float acc = bf2f(h[(size_t)i * F_OUT + lane]) * di * di;
    int s = offs[i], e = offs[i + 1];
    for (int u = s; u < e; u += 8) {
        int2 a[8];
        #pragma unroll
        for (int q = 0; q < 8; ++q) a[q] = jw[u + q];
        float hv[8];
        #pragma unroll
        for (int q = 0; q < 8; ++q)
            hv[q] = bf2f(h[(size_t)a[q].x * F_OUT + lane]);
        #pragma unroll
        for (int q = 0; q < 8; ++q) {
            float ww = (u + q < e) ? __int_as_float(a[q].y) * di : 0.f;
            acc += hv[q] * ww;
        }
    }
    acc += bias[lane];
    float m = acc;
    #pragma unroll
    for (int o = 32; o >= 1; o >>= 1) m = fmaxf(m, __shfl_xor(m, o, 64));
    float ex = expf(acc - m);
    float ssum = ex;
    #pragma unroll
    for (int o = 32; o >= 1; o >>= 1) ssum += __shfl_xor(ssum, o, 64);
    outm[(size_t)i * F_OUT + lane] = acc - m - logf(ssum);
}

extern "C" void kernel_launch(void* const* d_in, const int* in_sizes, int n_in,
                              void* d_out, int out_size, void* d_ws, size_t ws_size,
                              hipStream_t stream) {
    const float* x  = (const float*)d_in[0];
    const int*   ei = (const int*)d_in[1];
    const float* W1 = (const float*)d_in[2];
    const float* b1 = (const float*)d_in[3];
    const float* W2 = (const float*)d_in[4];
    const float* b2 = (const float*)d_in[5];
    float* out = (float*)d_out;

    int N = in_sizes[0] / F_IN;   // 50000
    int E = in_sizes[1] / 2;      // 800000
    const int* src = ei;
    const int* dst = ei + E;

    // workspace layout (16B aligned by construction)
    ushort* w1t = (ushort*)d_ws;                        // 256*512
    ushort* w2t = w1t + F_HID * F_IN;                   // 64*256
    ushort* h1  = w2t + F_OUT * F_HID;                  // N*256 bf16
    ushort* a1  = h1 + (size_t)N * F_HID;               // N*256 bf16
    int*    deg = (int*)(a1 + (size_t)N * F_HID);       // N
    float*  dinv = (float*)(deg + N);                   // N
    int*    offs = (int*)(dinv + N);                    // N+1
    int*    cursor = offs + N + 1;                      // N
    int*    bsums  = cursor + N;                        // 256
    int2*   jw = (int2*)(((uintptr_t)(bsums + 256) + 7) & ~(uintptr_t)7);  // E+16
    ushort* h2 = h1;     // alias: h1 dead after agg1

    int nch = (N + 255) / 256;

    hipMemsetAsync(deg, 0, sizeof(int) * N, stream);
    k_deg <<<(E + 255) / 256, 256, 0, stream>>>(dst, deg, E);
    k_scan1<<<nch, 256, 0, stream>>>(deg, offs, bsums, dinv, N);
    k_scan2<<<1, 256, 0, stream>>>(bsums, nch);
    k_scan3<<<nch, 256, 0, stream>>>(offs, bsums, cursor, jw, N, E);
    k_fill<<<(E + 255) / 256, 256, 0, stream>>>(src, dst, cursor, jw, dinv, E);

    // weight transpose-casts (one launch)
    int ntc = F_IN * F_HID + F_HID * F_OUT;
    k_tcast2<<<(ntc + 255) / 256, 256, 0, stream>>>(W1, w1t, W2, w2t);

    // layer 1: fused cast+GEMM (no-LDS, 1564 blocks) + paired-gather aggregate
    k_gemm1<<<dim3(2, (N + 63) / 64), 256, 0, stream>>>(x, w1t, h1, N);
    k_agg1<<<(N + 3) / 4, 256, 0, stream>>>(h1, jw, offs, dinv, b1, a1, N);

    // layer 2: GEMM (no-LDS, 782 blocks) + aggregate + log_softmax
    k_gemm2<<<dim3(1, (N + 63) / 64), 256, 0, stream>>>(a1, w2t, h2, N);
    k_agg2<<<(N + 3) / 4, 256, 0, stream>>>(h2, jw, offs, dinv, b2, out, N);
}

// Round 12
// 265.401 us; speedup vs baseline: 1.2200x; 1.2200x over previous
//
#include <hip/hip_runtime.h>
#include <math.h>

#define F_IN  512
#define F_HID 256
#define F_OUT 64

typedef __attribute__((ext_vector_type(8))) short bf16x8;
typedef __attribute__((ext_vector_type(4))) float f32x4;

#define GLOBAL_AS __attribute__((address_space(1)))
#define LDS_AS    __attribute__((address_space(3)))

__device__ __forceinline__ void gload_lds16(const void* g, void* l) {
    __builtin_amdgcn_global_load_lds((const GLOBAL_AS uint32_t*)g,
                                     (LDS_AS uint32_t*)l, 16, 0, 0);
}

__device__ __forceinline__ ushort f2bf(float f) {
    union { float f; uint32_t u; } v; v.f = f;
    uint32_t r = (v.u + 0x7FFFu + ((v.u >> 16) & 1u)) >> 16;
    return (ushort)r;
}

__device__ __forceinline__ float bf2f(ushort u) {
    union { uint32_t u; float f; } v; v.u = ((uint32_t)u) << 16;
    return v.f;
}

__device__ __forceinline__ bf16x8 conv8(float4 a, float4 b) {
    bf16x8 c;
    c[0] = (short)f2bf(a.x); c[1] = (short)f2bf(a.y);
    c[2] = (short)f2bf(a.z); c[3] = (short)f2bf(a.w);
    c[4] = (short)f2bf(b.x); c[5] = (short)f2bf(b.y);
    c[6] = (short)f2bf(b.z); c[7] = (short)f2bf(b.w);
    return c;
}

// ---------------- degree ----------------
__global__ void k_deg(const int* __restrict__ dst, int* __restrict__ deg, int E) {
    int e = blockIdx.x * 256 + threadIdx.x;
    if (e < E) atomicAdd(&deg[dst[e]], 1);
}

// ---------------- scan level 1 (+ dinv fused) ----------------
__global__ void k_scan1(const int* __restrict__ deg, int* __restrict__ offs,
                        int* __restrict__ bsums, float* __restrict__ dinv, int N) {
    __shared__ int s[256];
    int tid = threadIdx.x;
    int i = blockIdx.x * 256 + tid;
    int v = (i < N) ? deg[i] : 0;
    if (i < N) dinv[i] = rsqrtf((float)(v + 1));   // +1 self loop
    s[tid] = v; __syncthreads();
    for (int d = 1; d < 256; d <<= 1) {
        int t = (tid >= d) ? s[tid - d] : 0;
        __syncthreads();
        s[tid] += t;
        __syncthreads();
    }
    if (i < N) offs[i] = s[tid] - v;
    if (tid == 255) bsums[blockIdx.x] = s[255];
}

__global__ void k_scan2(int* __restrict__ bsums, int n) {
    __shared__ int s[256];
    int tid = threadIdx.x;
    int v = (tid < n) ? bsums[tid] : 0;
    s[tid] = v; __syncthreads();
    for (int d = 1; d < 256; d <<= 1) {
        int t = (tid >= d) ? s[tid - d] : 0;
        __syncthreads();
        s[tid] += t;
        __syncthreads();
    }
    if (tid < n) bsums[tid] = s[tid] - v;
}

__global__ void k_scan3(int* __restrict__ offs, const int* __restrict__ bsums,
                        int* __restrict__ cursor, int2* __restrict__ jw, int N, int E) {
    int i = blockIdx.x * 256 + threadIdx.x;
    if (i < N) {
        int o = offs[i] + bsums[i >> 8];
        offs[i] = o;
        cursor[i] = o;
    }
    if (i == 0) offs[N] = E;
    if (i < 16) jw[E + i] = make_int2(0, 0);   // pad: row 0, weight 0
}

// fill packed (src_index, dinv[src]) per CSR slot
__global__ void k_fill(const int* __restrict__ src, const int* __restrict__ dst,
                       int* __restrict__ cursor, int2* __restrict__ jw,
                       const float* __restrict__ dinv, int E) {
    int e = blockIdx.x * 256 + threadIdx.x;
    if (e < E) {
        int s = src[e];
        int pos = atomicAdd(&cursor[dst[e]], 1);
        jw[pos] = make_int2(s, __float_as_int(dinv[s]));
    }
}

// ---------------- weight transpose-casts (W1 and W2 in one launch) ----------------
__global__ void k_tcast2(const float* __restrict__ W1, ushort* __restrict__ w1t,
                         const float* __restrict__ W2, ushort* __restrict__ w2t) {
    int idx = blockIdx.x * 256 + threadIdx.x;
    const int n1 = F_IN * F_HID;
    if (idx < n1) {
        int n = idx / F_IN, k = idx - n * F_IN;
        w1t[idx] = f2bf(W1[(size_t)k * F_HID + n]);
    } else {
        int t = idx - n1;
        if (t < F_HID * F_OUT) {
            int n = t / F_HID, k = t - n * F_HID;
            w2t[t] = f2bf(W2[(size_t)k * F_OUT + n]);
        }
    }
}

// ---------------- GEMM1: h1[M,256] = bf16( fp32 x[M,512] @ w1t^T ) ----------------
// Triple-buffered counted-vmcnt pipeline (T4): all staging via global_load_lds
// (A staged as RAW fp32, converted at fragment-read). Loop: s_waitcnt vmcnt(4)
// -> raw s_barrier -> sched_barrier(0) -> stage(t+2) -> compute(t). Loads for
// tile t+1 stay in flight across the barrier (never vmcnt(0) mid-loop).
// A: XOR-swizzled via pre-swizzled global source (conflict-free frag reads).
// B: r9's chunk-XOR scheme. BM=64 x BN=128, 4 waves 2x2, 48KB LDS.
__global__ __launch_bounds__(256) void k_gemm1(
        const float* __restrict__ A, const ushort* __restrict__ Bt,
        ushort* __restrict__ C, int M) {
    constexpr int K = F_IN, Nc = F_HID, NT = K / 32;
    __shared__ float  Asf[3][64 * 32];
    __shared__ ushort Bsm[3][128 * 32];
    const int tid  = threadIdx.x;
    const int wave = tid >> 6, lane = tid & 63;
    const int wr = wave & 1, wc = wave >> 1;
    const int brow = blockIdx.y * 64, bcol = blockIdx.x * 128;
    const int l15 = lane & 15, hi = lane >> 4;

    // A staging map: 2 instrs, slots d = tid + l*256; row = d>>3, slot16 = tid&7.
    // Pre-swizzled source: physical slot holds logical bytes (slot*16)^((row&7)<<4).
    const int aslot = tid & 7;
    const int arow0 = tid >> 3;                       // l=0 rows 0..31, l=1 rows 32..63
    const int kf = (((aslot * 16) ^ ((arow0 & 7) << 4)) >> 2);   // same for both l (32 = 0 mod 8)
    int ar0 = brow + arow0;      if (ar0 >= M) ar0 = M - 1;
    int ar1 = brow + arow0 + 32; if (ar1 >= M) ar1 = M - 1;
    const float* ap0 = &A[(size_t)ar0 * K + kf];
    const float* ap1 = &A[(size_t)ar1 * K + kf];
    // B staging map (r9 chunk-XOR): row-in-group = tid>>2, chunk = tid&3.
    const int csrc = (tid & 3) ^ ((tid >> 3) & 3);
    const ushort* bp0 = &Bt[(size_t)(bcol + (tid >> 2)) * K + csrc * 8];
    const ushort* bp1 = &Bt[(size_t)(bcol + 64 + (tid >> 2)) * K + csrc * 8];

    f32x4 acc[2][4];
    #pragma unroll
    for (int m = 0; m < 2; ++m)
        #pragma unroll
        for (int n = 0; n < 4; ++n) acc[m][n] = (f32x4){0.f, 0.f, 0.f, 0.f};

    #define STAGE1(buf, t)                                                        \
        do {                                                                      \
            const int _k0 = (t) * 32;                                             \
            gload_lds16(ap0 + _k0, &Asf[buf][(0 * 256 + wave * 64) * 4]);         \
            gload_lds16(ap1 + _k0, &Asf[buf][(1 * 256 + wave * 64) * 4]);         \
            gload_lds16(bp0 + _k0, &Bsm[buf][(0 * 256 + wave * 64) * 8]);         \
            gload_lds16(bp1 + _k0, &Bsm[buf][(1 * 256 + wave * 64) * 8]);         \
        } while (0)

    STAGE1(0, 0);
    STAGE1(1, 1);

    const int swA = (l15 & 7) << 4;
    const int kbB = (hi ^ ((l15 >> 1) & 3)) * 16;

    #pragma unroll
    for (int t = 0; t < NT; ++t) {
        if (t < NT - 1) asm volatile("s_waitcnt vmcnt(4)" ::: "memory");
        else            asm volatile("s_waitcnt vmcnt(0)" ::: "memory");
        __builtin_amdgcn_s_barrier();
        __builtin_amdgcn_sched_barrier(0);
        if (t + 2 < NT) STAGE1((t + 2) % 3, t + 2);
        const int buf = t % 3;
        bf16x8 af[2], bfr[4];
        #pragma unroll
        for (int m = 0; m < 2; ++m) {
            const int row = wr * 32 + l15 + m * 16;
            const char* base = (const char*)&Asf[buf][row * 32];
            float4 f0 = *(const float4*)(base + ((hi * 32) ^ swA));
            float4 f1 = *(const float4*)(base + ((hi * 32 + 16) ^ swA));
            af[m] = conv8(f0, f1);
        }
        #pragma unroll
        for (int n = 0; n < 4; ++n) {
            const int row = wc * 64 + l15 + n * 16;
            bfr[n] = *(const bf16x8*)((const char*)&Bsm[buf][row * 32] + kbB);
        }
        #pragma unroll
        for (int m = 0; m < 2; ++m)
            #pragma unroll
            for (int n = 0; n < 4; ++n)
                acc[m][n] = __builtin_amdgcn_mfma_f32_16x16x32_bf16(af[m], bfr[n], acc[m][n], 0, 0, 0);
    }
    #undef STAGE1

    const int crow0 = brow + wr * 32 + hi * 4;
    const int ccol0 = bcol + wc * 64 + l15;
    #pragma unroll
    for (int m = 0; m < 2; ++m)
        #pragma unroll
        for (int n = 0; n < 4; ++n)
            #pragma unroll
            for (int j = 0; j < 4; ++j) {
                int row = crow0 + m * 16 + j;
                if (row < M) C[(size_t)row * Nc + ccol0 + n * 16] = f2bf(acc[m][n][j]);
            }
}

// ---------------- bf16 MFMA GEMM2: C[M,Nc] = A[M,K] @ Bt[Nc,K]^T (bf16 out) ----------------
template<int WR, int WC, int MR, int NR>
__global__ __launch_bounds__(256) void k_gemm_bf16(
        const ushort* __restrict__ A, const ushort* __restrict__ Bt,
        ushort* __restrict__ C, int M, int K, int Nc) {
    constexpr int BM = WR * MR * 16;
    constexpr int BN = WC * NR * 16;
    __shared__ ushort As[BM * 32];
    __shared__ ushort Bs[BN * 32];
    const int tid  = threadIdx.x;
    const int wave = tid >> 6, lane = tid & 63;
    const int wr = wave % WR, wc = wave / WR;
    const int brow = blockIdx.y * BM, bcol = blockIdx.x * BN;

    f32x4 acc[MR][NR];
    #pragma unroll
    for (int m = 0; m < MR; ++m)
        #pragma unroll
        for (int n = 0; n < NR; ++n) acc[m][n] = (f32x4){0.f, 0.f, 0.f, 0.f};

    const int srow = tid >> 2;
    const int scol = (tid & 3) * 8;
    const int kq  = (lane >> 4) * 8;
    const int rA0 = wr * MR * 16 + (lane & 15);
    const int rB0 = wc * NR * 16 + (lane & 15);

    for (int k0 = 0; k0 < K; k0 += 32) {
        #pragma unroll
        for (int l = 0; l < BM / 64; ++l) {
            int row = brow + l * 64 + srow;
            if (row >= M) row = M - 1;
            gload_lds16(&A[(size_t)row * K + k0 + scol], &As[l * 2048 + wave * 512]);
        }
        #pragma unroll
        for (int l = 0; l < BN / 64; ++l) {
            int row = bcol + l * 64 + srow;
            gload_lds16(&Bt[(size_t)row * K + k0 + scol], &Bs[l * 2048 + wave * 512]);
        }
        __syncthreads();
        bf16x8 af[MR], bfr[NR];
        #pragma unroll
        for (int m = 0; m < MR; ++m)
            af[m] = *(const bf16x8*)&As[(rA0 + m * 16) * 32 + kq];
        #pragma unroll
        for (int n = 0; n < NR; ++n)
            bfr[n] = *(const bf16x8*)&Bs[(rB0 + n * 16) * 32 + kq];
        #pragma unroll
        for (int m = 0; m < MR; ++m)
            #pragma unroll
            for (int n = 0; n < NR; ++n)
                acc[m][n] = __builtin_amdgcn_mfma_f32_16x16x32_bf16(af[m], bfr[n], acc[m][n], 0, 0, 0);
        __syncthreads();
    }

    const int crow0 = brow + wr * MR * 16 + (lane >> 4) * 4;
    const int ccol0 = bcol + wc * NR * 16 + (lane & 15);
    #pragma unroll
    for (int m = 0; m < MR; ++m)
        #pragma unroll
        for (int n = 0; n < NR; ++n)
            #pragma unroll
            for (int j = 0; j < 4; ++j) {
                int row = crow0 + m * 16 + j;
                if (row < M) C[(size_t)row * Nc + ccol0 + n * 16] = f2bf(acc[m][n][j]);
            }
}

// ---------------- layer-1 aggregation: paired-row gathers, 16 edges/iter ----------------
__global__ __launch_bounds__(256) void k_agg1(
        const ushort* __restrict__ h, const int2* __restrict__ jw,
        const int* __restrict__ offs, const float* __restrict__ dinv,
        const float* __restrict__ bias, ushort* __restrict__ outm, int N) {
    int wave = threadIdx.x >> 6, lane = threadIdx.x & 63;
    int i = blockIdx.x * 4 + wave;
    if (i >= N) return;
    int g = lane & 31;        // features g*8 .. g*8+7
    int p = lane >> 5;        // edge parity
    float di = dinv[i];
    float acc[8];
    {
        bf16x8 hv = *(const bf16x8*)&h[(size_t)i * F_HID + g * 8];
        float w = (p == 0) ? di * di : 0.f;     // self loop counted once
        #pragma unroll
        for (int k = 0; k < 8; ++k) acc[k] = bf2f((ushort)hv[k]) * w;
    }
    int s = offs[i], e = offs[i + 1];
    for (int u = s; u < e; u += 16) {
        int2 a[8];
        #pragma unroll
        for (int q = 0; q < 8; ++q) a[q] = jw[u + 2 * q + p];   // overrun -> pad/next-node, masked
        bf16x8 hv[8];
        #pragma unroll
        for (int q = 0; q < 8; ++q)
            hv[q] = *(const bf16x8*)&h[(size_t)a[q].x * F_HID + g * 8];
        #pragma unroll
        for (int q = 0; q < 8; ++q) {
            float ww = (u + 2 * q + p < e) ? __int_as_float(a[q].y) * di : 0.f;
            #pragma unroll
            for (int k = 0; k < 8; ++k) acc[k] += bf2f((ushort)hv[q][k]) * ww;
        }
    }
    #pragma unroll
    for (int k = 0; k < 8; ++k) acc[k] += __shfl_xor(acc[k], 32, 64);
    if (p == 0) {
        float4 b0 = *(const float4*)&bias[g * 8];
        float4 b1 = *(const float4*)&bias[g * 8 + 4];
        bf16x8 o;
        o[0] = (short)f2bf(fmaxf(acc[0] + b0.x, 0.f));
        o[1] = (short)f2bf(fmaxf(acc[1] + b0.y, 0.f));
        o[2] = (short)f2bf(fmaxf(acc[2] + b0.z, 0.f));
        o[3] = (short)f2bf(fmaxf(acc[3] + b0.w, 0.f));
        o[4] = (short)f2bf(fmaxf(acc[4] + b1.x, 0.f));
        o[5] = (short)f2bf(fmaxf(acc[5] + b1.y, 0.f));
        o[6] = (short)f2bf(fmaxf(acc[6] + b1.z, 0.f));
        o[7] = (short)f2bf(fmaxf(acc[7] + b1.w, 0.f));
        *(bf16x8*)&outm[(size_t)i * F_HID + g * 8] = o;
    }
}

// ---------------- layer-2 aggregation + bias + log_softmax: wave per node, 8-unroll ----------------
__global__ __launch_bounds__(256) void k_agg2(
        const ushort* __restrict__ h, const int2* __restrict__ jw,
        const int* __restrict__ offs, const float* __restrict__ dinv,
        const float* __restrict__ bias, float* __restrict__ outm, int N) {
    int wave = threadIdx.x >> 6, lane = threadIdx.x & 63;
    int i = blockIdx.x * 4 + wave;
    if (i >= N) return;
    float di = dinv[i];
    float acc = bf2f(h[(size_t)i * F_OUT + lane]) * di * di;
    int s = offs[i], e = offs[i + 1];
    for (int u = s; u < e; u += 8) {
        int2 a[8];
        #pragma unroll
        for (int q = 0; q < 8; ++q) a[q] = jw[u + q];
        float hv[8];
        #pragma unroll
        for (int q = 0; q < 8; ++q)
            hv[q] = bf2f(h[(size_t)a[q].x * F_OUT + lane]);
        #pragma unroll
        for (int q = 0; q < 8; ++q) {
            float ww = (u + q < e) ? __int_as_float(a[q].y) * di : 0.f;
            acc += hv[q] * ww;
        }
    }
    acc += bias[lane];
    float m = acc;
    #pragma unroll
    for (int o = 32; o >= 1; o >>= 1) m = fmaxf(m, __shfl_xor(m, o, 64));
    float ex = expf(acc - m);
    float ssum = ex;
    #pragma unroll
    for (int o = 32; o >= 1; o >>= 1) ssum += __shfl_xor(ssum, o, 64);
    outm[(size_t)i * F_OUT + lane] = acc - m - logf(ssum);
}

extern "C" void kernel_launch(void* const* d_in, const int* in_sizes, int n_in,
                              void* d_out, int out_size, void* d_ws, size_t ws_size,
                              hipStream_t stream) {
    const float* x  = (const float*)d_in[0];
    const int*   ei = (const int*)d_in[1];
    const float* W1 = (const float*)d_in[2];
    const float* b1 = (const float*)d_in[3];
    const float* W2 = (const float*)d_in[4];
    const float* b2 = (const float*)d_in[5];
    float* out = (float*)d_out;

    int N = in_sizes[0] / F_IN;   // 50000
    int E = in_sizes[1] / 2;      // 800000
    const int* src = ei;
    const int* dst = ei + E;

    // workspace layout (16B aligned by construction)
    ushort* w1t = (ushort*)d_ws;                        // 256*512
    ushort* w2t = w1t + F_HID * F_IN;                   // 64*256
    ushort* h1  = w2t + F_OUT * F_HID;                  // N*256 bf16
    ushort* a1  = h1 + (size_t)N * F_HID;               // N*256 bf16
    int*    deg = (int*)(a1 + (size_t)N * F_HID);       // N
    float*  dinv = (float*)(deg + N);                   // N
    int*    offs = (int*)(dinv + N);                    // N+1
    int*    cursor = offs + N + 1;                      // N
    int*    bsums  = cursor + N;                        // 256
    int2*   jw = (int2*)(((uintptr_t)(bsums + 256) + 7) & ~(uintptr_t)7);  // E+16
    ushort* h2 = h1;     // alias: h1 dead after agg1

    int nch = (N + 255) / 256;

    hipMemsetAsync(deg, 0, sizeof(int) * N, stream);
    k_deg <<<(E + 255) / 256, 256, 0, stream>>>(dst, deg, E);
    k_scan1<<<nch, 256, 0, stream>>>(deg, offs, bsums, dinv, N);
    k_scan2<<<1, 256, 0, stream>>>(bsums, nch);
    k_scan3<<<nch, 256, 0, stream>>>(offs, bsums, cursor, jw, N, E);
    k_fill<<<(E + 255) / 256, 256, 0, stream>>>(src, dst, cursor, jw, dinv, E);

    // weight transpose-casts (one launch)
    int ntc = F_IN * F_HID + F_HID * F_OUT;
    k_tcast2<<<(ntc + 255) / 256, 256, 0, stream>>>(W1, w1t, W2, w2t);

    // layer 1: fused cast+GEMM (triple-buffer counted-vmcnt) + paired-gather aggregate
    k_gemm1<<<dim3(2, (N + 63) / 64), 256, 0, stream>>>(x, w1t, h1, N);
    k_agg1<<<(N + 3) / 4, 256, 0, stream>>>(h1, jw, offs, dinv, b1, a1, N);

    // layer 2: GEMM (64x64, 782 blocks) + aggregate + log_softmax
    k_gemm_bf16<4, 1, 1, 4><<<dim3(1, (N + 63) / 64), 256, 0, stream>>>(
        a1, w2t, h2, N, F_HID, F_OUT);
    k_agg2<<<(N + 3) / 4, 256, 0, stream>>>(h2, jw, offs, dinv, b2, out, N);
}

// Round 13
// 247.643 us; speedup vs baseline: 1.3075x; 1.0717x over previous
//
#include <hip/hip_runtime.h>
#include <math.h>

#define F_IN  512
#define F_HID 256
#define F_OUT 64

typedef __attribute__((ext_vector_type(8))) short bf16x8;
typedef __attribute__((ext_vector_type(4))) float f32x4;

#define GLOBAL_AS __attribute__((address_space(1)))
#define LDS_AS    __attribute__((address_space(3)))

__device__ __forceinline__ void gload_lds16(const void* g, void* l) {
    __builtin_amdgcn_global_load_lds((const GLOBAL_AS uint32_t*)g,
                                     (LDS_AS uint32_t*)l, 16, 0, 0);
}

__device__ __forceinline__ ushort f2bf(float f) {
    union { float f; uint32_t u; } v; v.f = f;
    uint32_t r = (v.u + 0x7FFFu + ((v.u >> 16) & 1u)) >> 16;
    return (ushort)r;
}

__device__ __forceinline__ float bf2f(ushort u) {
    union { uint32_t u; float f; } v; v.u = ((uint32_t)u) << 16;
    return v.f;
}

__device__ __forceinline__ bf16x8 conv8(float4 a, float4 b) {
    bf16x8 c;
    c[0] = (short)f2bf(a.x); c[1] = (short)f2bf(a.y);
    c[2] = (short)f2bf(a.z); c[3] = (short)f2bf(a.w);
    c[4] = (short)f2bf(b.x); c[5] = (short)f2bf(b.y);
    c[6] = (short)f2bf(b.z); c[7] = (short)f2bf(b.w);
    return c;
}

// ---------------- degree ----------------
__global__ void k_deg(const int* __restrict__ dst, int* __restrict__ deg, int E) {
    int e = blockIdx.x * 256 + threadIdx.x;
    if (e < E) atomicAdd(&deg[dst[e]], 1);
}

// ---------------- scan level 1 (+ dinv fused) ----------------
__global__ void k_scan1(const int* __restrict__ deg, int* __restrict__ offs,
                        int* __restrict__ bsums, float* __restrict__ dinv, int N) {
    __shared__ int s[256];
    int tid = threadIdx.x;
    int i = blockIdx.x * 256 + tid;
    int v = (i < N) ? deg[i] : 0;
    if (i < N) dinv[i] = rsqrtf((float)(v + 1));   // +1 self loop
    s[tid] = v; __syncthreads();
    for (int d = 1; d < 256; d <<= 1) {
        int t = (tid >= d) ? s[tid - d] : 0;
        __syncthreads();
        s[tid] += t;
        __syncthreads();
    }
    if (i < N) offs[i] = s[tid] - v;
    if (tid == 255) bsums[blockIdx.x] = s[255];
}

__global__ void k_scan2(int* __restrict__ bsums, int n) {
    __shared__ int s[256];
    int tid = threadIdx.x;
    int v = (tid < n) ? bsums[tid] : 0;
    s[tid] = v; __syncthreads();
    for (int d = 1; d < 256; d <<= 1) {
        int t = (tid >= d) ? s[tid - d] : 0;
        __syncthreads();
        s[tid] += t;
        __syncthreads();
    }
    if (tid < n) bsums[tid] = s[tid] - v;
}

__global__ void k_scan3(int* __restrict__ offs, const int* __restrict__ bsums,
                        int* __restrict__ cursor, int2* __restrict__ jw, int N, int E) {
    int i = blockIdx.x * 256 + threadIdx.x;
    if (i < N) {
        int o = offs[i] + bsums[i >> 8];
        offs[i] = o;
        cursor[i] = o;
    }
    if (i == 0) offs[N] = E;
    if (i < 16) jw[E + i] = make_int2(0, 0);   // pad: row 0, weight 0
}

// fill packed (src_index, dinv[src]) per CSR slot
__global__ void k_fill(const int* __restrict__ src, const int* __restrict__ dst,
                       int* __restrict__ cursor, int2* __restrict__ jw,
                       const float* __restrict__ dinv, int E) {
    int e = blockIdx.x * 256 + threadIdx.x;
    if (e < E) {
        int s = src[e];
        int pos = atomicAdd(&cursor[dst[e]], 1);
        jw[pos] = make_int2(s, __float_as_int(dinv[s]));
    }
}

// ---------------- weight transpose-casts (W1 and W2 in one launch) ----------------
__global__ void k_tcast2(const float* __restrict__ W1, ushort* __restrict__ w1t,
                         const float* __restrict__ W2, ushort* __restrict__ w2t) {
    int idx = blockIdx.x * 256 + threadIdx.x;
    const int n1 = F_IN * F_HID;
    if (idx < n1) {
        int n = idx / F_IN, k = idx - n * F_IN;
        w1t[idx] = f2bf(W1[(size_t)k * F_HID + n]);
    } else {
        int t = idx - n1;
        if (t < F_HID * F_OUT) {
            int n = t / F_HID, k = t - n * F_HID;
            w2t[t] = f2bf(W2[(size_t)k * F_OUT + n]);
        }
    }
}

// ---------------- GEMM1: h1[M,256] = bf16( fp32 x[M,512] @ w1t^T ) ----------------
// r9 structure (best measured): BM=64 x BN=128, 4 waves 2x2, double-buffered,
// B chunk-XOR swizzle, one barrier/iter. NEW: XCD pair-swizzle — the two
// column-blocks sharing an A row-panel are mapped 8 linear ids apart so the
// round-robin dispatcher puts them on the SAME XCD (one L2 copy of the panel).
__global__ __launch_bounds__(256) void k_gemm1(
        const float* __restrict__ A, const ushort* __restrict__ Bt,
        ushort* __restrict__ C, int M, int nyblk) {
    constexpr int K = F_IN, Nc = F_HID, BM = 64, NT = K / 32;
    constexpr int ASTR = 36;
    __shared__ ushort As[2][BM * ASTR];
    __shared__ ushort Bs[2][128 * 32];
    const int tid  = threadIdx.x;
    const int wave = tid >> 6, lane = tid & 63;
    const int wr = wave & 1, wc = wave >> 1;

    // --- XCD pair-swizzle: L -> (bx, by) with pair members 8 apart ---
    int L = blockIdx.x;
    int nfull = (2 * nyblk) & ~15;          // largest multiple of 16
    int bx, by;
    if (L < nfull) {
        bx = (L >> 3) & 1;
        by = (L >> 4) * 8 + (L & 7);
    } else {
        int t = L - nfull;
        bx = t & 1;
        by = nfull / 2 + (t >> 1);
    }
    const int brow = by * BM, bcol = bx * 128;

    f32x4 acc[2][4];
    #pragma unroll
    for (int m = 0; m < 2; ++m)
        #pragma unroll
        for (int n = 0; n < 4; ++n) acc[m][n] = (f32x4){0.f, 0.f, 0.f, 0.f};

    // A stage: 4 thr/row, 8 fp32 (2 float4) each
    const int arow = tid >> 2;
    const int akc  = (tid & 3) * 8;
    int agrow = brow + arow; if (agrow >= M) agrow = M - 1;
    const float4* ap = (const float4*)&A[(size_t)agrow * K + akc];   // iter t: ap[t*8+q]
    // B stage: 4 thr/row over two 64-row groups; chunk-XOR pre-swizzled source
    const int csrc = (tid & 3) ^ ((tid >> 3) & 3);
    const ushort* bp0 = &Bt[(size_t)(bcol + (tid >> 2)) * K + csrc * 8];
    const ushort* bp1 = &Bt[(size_t)(bcol + 64 + (tid >> 2)) * K + csrc * 8];

    const int kqA = (lane >> 4) * 8;
    const int kqB = ((lane >> 4) ^ ((lane >> 1) & 3)) * 8;   // undo store swizzle
    const int rA0 = wr * 32 + (lane & 15);
    const int rB0 = wc * 64 + (lane & 15);

    // ---- prologue: stage t=0 into buf 0 ----
    {
        float4 v0 = ap[0], v1 = ap[1];
        *(bf16x8*)&As[0][arow * ASTR + akc] = conv8(v0, v1);
        gload_lds16(bp0, &Bs[0][wave * 512]);
        gload_lds16(bp1, &Bs[0][2048 + wave * 512]);
    }
    __syncthreads();

    #pragma unroll
    for (int t = 0; t < NT; ++t) {
        const int b = t & 1;
        if (t + 1 < NT) {
            gload_lds16(bp0 + (t + 1) * 32, &Bs[b ^ 1][wave * 512]);
            gload_lds16(bp1 + (t + 1) * 32, &Bs[b ^ 1][2048 + wave * 512]);
            float4 v0 = ap[(t + 1) * 8], v1 = ap[(t + 1) * 8 + 1];
            *(bf16x8*)&As[b ^ 1][arow * ASTR + akc] = conv8(v0, v1);
        }
        bf16x8 af[2], bfr[4];
        #pragma unroll
        for (int m = 0; m < 2; ++m)
            af[m] = *(const bf16x8*)&As[b][(rA0 + m * 16) * ASTR + kqA];
        #pragma unroll
        for (int n = 0; n < 4; ++n)
            bfr[n] = *(const bf16x8*)&Bs[b][(rB0 + n * 16) * 32 + kqB];
        #pragma unroll
        for (int m = 0; m < 2; ++m)
            #pragma unroll
            for (int n = 0; n < 4; ++n)
                acc[m][n] = __builtin_amdgcn_mfma_f32_16x16x32_bf16(af[m], bfr[n], acc[m][n], 0, 0, 0);
        if (t + 1 < NT) __syncthreads();
    }

    const int crow0 = brow + wr * 32 + (lane >> 4) * 4;
    const int ccol0 = bcol + wc * 64 + (lane & 15);
    #pragma unroll
    for (int m = 0; m < 2; ++m)
        #pragma unroll
        for (int n = 0; n < 4; ++n)
            #pragma unroll
            for (int j = 0; j < 4; ++j) {
                int row = crow0 + m * 16 + j;
                if (row < M) C[(size_t)row * Nc + ccol0 + n * 16] = f2bf(acc[m][n][j]);
            }
}

// ---------------- bf16 MFMA GEMM2: C[M,Nc] = A[M,K] @ Bt[Nc,K]^T (bf16 out) ----------------
template<int WR, int WC, int MR, int NR>
__global__ __launch_bounds__(256) void k_gemm_bf16(
        const ushort* __restrict__ A, const ushort* __restrict__ Bt,
        ushort* __restrict__ C, int M, int K, int Nc) {
    constexpr int BM = WR * MR * 16;
    constexpr int BN = WC * NR * 16;
    __shared__ ushort As[BM * 32];
    __shared__ ushort Bs[BN * 32];
    const int tid  = threadIdx.x;
    const int wave = tid >> 6, lane = tid & 63;
    const int wr = wave % WR, wc = wave / WR;
    const int brow = blockIdx.y * BM, bcol = blockIdx.x * BN;

    f32x4 acc[MR][NR];
    #pragma unroll
    for (int m = 0; m < MR; ++m)
        #pragma unroll
        for (int n = 0; n < NR; ++n) acc[m][n] = (f32x4){0.f, 0.f, 0.f, 0.f};

    const int srow = tid >> 2;
    const int scol = (tid & 3) * 8;
    const int kq  = (lane >> 4) * 8;
    const int rA0 = wr * MR * 16 + (lane & 15);
    const int rB0 = wc * NR * 16 + (lane & 15);

    for (int k0 = 0; k0 < K; k0 += 32) {
        #pragma unroll
        for (int l = 0; l < BM / 64; ++l) {
            int row = brow + l * 64 + srow;
            if (row >= M) row = M - 1;
            gload_lds16(&A[(size_t)row * K + k0 + scol], &As[l * 2048 + wave * 512]);
        }
        #pragma unroll
        for (int l = 0; l < BN / 64; ++l) {
            int row = bcol + l * 64 + srow;
            gload_lds16(&Bt[(size_t)row * K + k0 + scol], &Bs[l * 2048 + wave * 512]);
        }
        __syncthreads();
        bf16x8 af[MR], bfr[NR];
        #pragma unroll
        for (int m = 0; m < MR; ++m)
            af[m] = *(const bf16x8*)&As[(rA0 + m * 16) * 32 + kq];
        #pragma unroll
        for (int n = 0; n < NR; ++n)
            bfr[n] = *(const bf16x8*)&Bs[(rB0 + n * 16) * 32 + kq];
        #pragma unroll
        for (int m = 0; m < MR; ++m)
            #pragma unroll
            for (int n = 0; n < NR; ++n)
                acc[m][n] = __builtin_amdgcn_mfma_f32_16x16x32_bf16(af[m], bfr[n], acc[m][n], 0, 0, 0);
        __syncthreads();
    }

    const int crow0 = brow + wr * MR * 16 + (lane >> 4) * 4;
    const int ccol0 = bcol + wc * NR * 16 + (lane & 15);
    #pragma unroll
    for (int m = 0; m < MR; ++m)
        #pragma unroll
        for (int n = 0; n < NR; ++n)
            #pragma unroll
            for (int j = 0; j < 4; ++j) {
                int row = crow0 + m * 16 + j;
                if (row < M) C[(size_t)row * Nc + ccol0 + n * 16] = f2bf(acc[m][n][j]);
            }
}

// ---------------- layer-1 aggregation: paired-row gathers, 16 edges/iter ----------------
__global__ __launch_bounds__(256) void k_agg1(
        const ushort* __restrict__ h, const int2* __restrict__ jw,
        const int* __restrict__ offs, const float* __restrict__ dinv,
        const float* __restrict__ bias, ushort* __restrict__ outm, int N) {
    int wave = threadIdx.x >> 6, lane = threadIdx.x & 63;
    int i = blockIdx.x * 4 + wave;
    if (i >= N) return;
    int g = lane & 31;        // features g*8 .. g*8+7
    int p = lane >> 5;        // edge parity
    float di = dinv[i];
    float acc[8];
    {
        bf16x8 hv = *(const bf16x8*)&h[(size_t)i * F_HID + g * 8];
        float w = (p == 0) ? di * di : 0.f;     // self loop counted once
        #pragma unroll
        for (int k = 0; k < 8; ++k) acc[k] = bf2f((ushort)hv[k]) * w;
    }
    int s = offs[i], e = offs[i + 1];
    for (int u = s; u < e; u += 16) {
        int2 a[8];
        #pragma unroll
        for (int q = 0; q < 8; ++q) a[q] = jw[u + 2 * q + p];   // overrun -> pad/next-node, masked
        bf16x8 hv[8];
        #pragma unroll
        for (int q = 0; q < 8; ++q)
            hv[q] = *(const bf16x8*)&h[(size_t)a[q].x * F_HID + g * 8];
        #pragma unroll
        for (int q = 0; q < 8; ++q) {
            float ww = (u + 2 * q + p < e) ? __int_as_float(a[q].y) * di : 0.f;
            #pragma unroll
            for (int k = 0; k < 8; ++k) acc[k] += bf2f((ushort)hv[q][k]) * ww;
        }
    }
    #pragma unroll
    for (int k = 0; k < 8; ++k) acc[k] += __shfl_xor(acc[k], 32, 64);
    if (p == 0) {
        float4 b0 = *(const float4*)&bias[g * 8];
        float4 b1 = *(const float4*)&bias[g * 8 + 4];
        bf16x8 o;
        o[0] = (short)f2bf(fmaxf(acc[0] + b0.x, 0.f));
        o[1] = (short)f2bf(fmaxf(acc[1] + b0.y, 0.f));
        o[2] = (short)f2bf(fmaxf(acc[2] + b0.z, 0.f));
        o[3] = (short)f2bf(fmaxf(acc[3] + b0.w, 0.f));
        o[4] = (short)f2bf(fmaxf(acc[4] + b1.x, 0.f));
        o[5] = (short)f2bf(fmaxf(acc[5] + b1.y, 0.f));
        o[6] = (short)f2bf(fmaxf(acc[6] + b1.z, 0.f));
        o[7] = (short)f2bf(fmaxf(acc[7] + b1.w, 0.f));
        *(bf16x8*)&outm[(size_t)i * F_HID + g * 8] = o;
    }
}

// ---------------- layer-2 aggregation + bias + log_softmax: wave per node, 8-unroll ----------------
__global__ __launch_bounds__(256) void k_agg2(
        const ushort* __restrict__ h, const int2* __restrict__ jw,
        const int* __restrict__ offs, const float* __restrict__ dinv,
        const float* __restrict__ bias, float* __restrict__ outm, int N) {
    int wave = threadIdx.x >> 6, lane = threadIdx.x & 63;
    int i = blockIdx.x * 4 + wave;
    if (i >= N) return;
    float di = dinv[i];
    float acc = bf2f(h[(size_t)i * F_OUT + lane]) * di * di;
    int s = offs[i], e = offs[i + 1];
    for (int u = s; u < e; u += 8) {
        int2 a[8];
        #pragma unroll
        for (int q = 0; q < 8; ++q) a[q] = jw[u + q];
        float hv[8];
        #pragma unroll
        for (int q = 0; q < 8; ++q)
            hv[q] = bf2f(h[(size_t)a[q].x * F_OUT + lane]);
        #pragma unroll
        for (int q = 0; q < 8; ++q) {
            float ww = (u + q < e) ? __int_as_float(a[q].y) * di : 0.f;
            acc += hv[q] * ww;
        }
    }
    acc += bias[lane];
    float m = acc;
    #pragma unroll
    for (int o = 32; o >= 1; o >>= 1) m = fmaxf(m, __shfl_xor(m, o, 64));
    float ex = expf(acc - m);
    float ssum = ex;
    #pragma unroll
    for (int o = 32; o >= 1; o >>= 1) ssum += __shfl_xor(ssum, o, 64);
    outm[(size_t)i * F_OUT + lane] = acc - m - logf(ssum);
}

extern "C" void kernel_launch(void* const* d_in, const int* in_sizes, int n_in,
                              void* d_out, int out_size, void* d_ws, size_t ws_size,
                              hipStream_t stream) {
    const float* x  = (const float*)d_in[0];
    const int*   ei = (const int*)d_in[1];
    const float* W1 = (const float*)d_in[2];
    const float* b1 = (const float*)d_in[3];
    const float* W2 = (const float*)d_in[4];
    const float* b2 = (const float*)d_in[5];
    float* out = (float*)d_out;

    int N = in_sizes[0] / F_IN;   // 50000
    int E = in_sizes[1] / 2;      // 800000
    const int* src = ei;
    const int* dst = ei + E;

    // workspace layout (16B aligned by construction)
    ushort* w1t = (ushort*)d_ws;                        // 256*512
    ushort* w2t = w1t + F_HID * F_IN;                   // 64*256
    ushort* h1  = w2t + F_OUT * F_HID;                  // N*256 bf16
    ushort* a1  = h1 + (size_t)N * F_HID;               // N*256 bf16
    int*    deg = (int*)(a1 + (size_t)N * F_HID);       // N
    float*  dinv = (float*)(deg + N);                   // N
    int*    offs = (int*)(dinv + N);                    // N+1
    int*    cursor = offs + N + 1;                      // N
    int*    bsums  = cursor + N;                        // 256
    int2*   jw = (int2*)(((uintptr_t)(bsums + 256) + 7) & ~(uintptr_t)7);  // E+16
    ushort* h2 = h1;     // alias: h1 dead after agg1

    int nch = (N + 255) / 256;

    hipMemsetAsync(deg, 0, sizeof(int) * N, stream);
    k_deg <<<(E + 255) / 256, 256, 0, stream>>>(dst, deg, E);
    k_scan1<<<nch, 256, 0, stream>>>(deg, offs, bsums, dinv, N);
    k_scan2<<<1, 256, 0, stream>>>(bsums, nch);
    k_scan3<<<nch, 256, 0, stream>>>(offs, bsums, cursor, jw, N, E);
    k_fill<<<(E + 255) / 256, 256, 0, stream>>>(src, dst, cursor, jw, dinv, E);

    // weight transpose-casts (one launch)
    int ntc = F_IN * F_HID + F_HID * F_OUT;
    k_tcast2<<<(ntc + 255) / 256, 256, 0, stream>>>(W1, w1t, W2, w2t);

    // layer 1: fused cast+GEMM (r9 structure + XCD pair-swizzle) + paired-16 aggregate
    int nyblk = (N + 63) / 64;
    k_gemm1<<<2 * nyblk, 256, 0, stream>>>(x, w1t, h1, N, nyblk);
    k_agg1<<<(N + 3) / 4, 256, 0, stream>>>(h1, jw, offs, dinv, b1, a1, N);

    // layer 2: GEMM (64x64 tile) + aggregate + log_softmax
    k_gemm_bf16<4, 1, 1, 4><<<dim3(1, (N + 63) / 64), 256, 0, stream>>>(
        a1, w2t, h2, N, F_HID, F_OUT);
    k_agg2<<<(N + 3) / 4, 256, 0, stream>>>(h2, jw, offs, dinv, b2, out, N);
}

// Round 14
// 243.593 us; speedup vs baseline: 1.3292x; 1.0166x over previous
//
#include <hip/hip_runtime.h>
#include <math.h>

#define F_IN  512
#define F_HID 256
#define F_OUT 64

typedef __attribute__((ext_vector_type(8))) short bf16x8;
typedef __attribute__((ext_vector_type(4))) short bf16x4;
typedef __attribute__((ext_vector_type(4))) float f32x4;

#define GLOBAL_AS __attribute__((address_space(1)))
#define LDS_AS    __attribute__((address_space(3)))

__device__ __forceinline__ void gload_lds16(const void* g, void* l) {
    __builtin_amdgcn_global_load_lds((const GLOBAL_AS uint32_t*)g,
                                     (LDS_AS uint32_t*)l, 16, 0, 0);
}

__device__ __forceinline__ ushort f2bf(float f) {
    union { float f; uint32_t u; } v; v.f = f;
    uint32_t r = (v.u + 0x7FFFu + ((v.u >> 16) & 1u)) >> 16;
    return (ushort)r;
}

__device__ __forceinline__ float bf2f(ushort u) {
    union { uint32_t u; float f; } v; v.u = ((uint32_t)u) << 16;
    return v.f;
}

__device__ __forceinline__ bf16x8 conv8(float4 a, float4 b) {
    bf16x8 c;
    c[0] = (short)f2bf(a.x); c[1] = (short)f2bf(a.y);
    c[2] = (short)f2bf(a.z); c[3] = (short)f2bf(a.w);
    c[4] = (short)f2bf(b.x); c[5] = (short)f2bf(b.y);
    c[6] = (short)f2bf(b.z); c[7] = (short)f2bf(b.w);
    return c;
}

// ---------------- degree ----------------
__global__ void k_deg(const int* __restrict__ dst, int* __restrict__ deg, int E) {
    int e = blockIdx.x * 256 + threadIdx.x;
    if (e < E) atomicAdd(&deg[dst[e]], 1);
}

// ---------------- scan level 1 (+ dinv fused) ----------------
__global__ void k_scan1(const int* __restrict__ deg, int* __restrict__ offs,
                        int* __restrict__ bsums, float* __restrict__ dinv, int N) {
    __shared__ int s[256];
    int tid = threadIdx.x;
    int i = blockIdx.x * 256 + tid;
    int v = (i < N) ? deg[i] : 0;
    if (i < N) dinv[i] = rsqrtf((float)(v + 1));   // +1 self loop
    s[tid] = v; __syncthreads();
    for (int d = 1; d < 256; d <<= 1) {
        int t = (tid >= d) ? s[tid - d] : 0;
        __syncthreads();
        s[tid] += t;
        __syncthreads();
    }
    if (i < N) offs[i] = s[tid] - v;
    if (tid == 255) bsums[blockIdx.x] = s[255];
}

__global__ void k_scan2(int* __restrict__ bsums, int n) {
    __shared__ int s[256];
    int tid = threadIdx.x;
    int v = (tid < n) ? bsums[tid] : 0;
    s[tid] = v; __syncthreads();
    for (int d = 1; d < 256; d <<= 1) {
        int t = (tid >= d) ? s[tid - d] : 0;
        __syncthreads();
        s[tid] += t;
        __syncthreads();
    }
    if (tid < n) bsums[tid] = s[tid] - v;
}

__global__ void k_scan3(int* __restrict__ offs, const int* __restrict__ bsums,
                        int* __restrict__ cursor, int2* __restrict__ jw, int N, int E) {
    int i = blockIdx.x * 256 + threadIdx.x;
    if (i < N) {
        int o = offs[i] + bsums[i >> 8];
        offs[i] = o;
        cursor[i] = o;
    }
    if (i == 0) offs[N] = E;
    if (i < 32) jw[E + i] = make_int2(0, 0);   // pad: row 0, weight 0 (agg2 overruns <=31)
}

// fill packed (src_index, dinv[src]) per CSR slot
__global__ void k_fill(const int* __restrict__ src, const int* __restrict__ dst,
                       int* __restrict__ cursor, int2* __restrict__ jw,
                       const float* __restrict__ dinv, int E) {
    int e = blockIdx.x * 256 + threadIdx.x;
    if (e < E) {
        int s = src[e];
        int pos = atomicAdd(&cursor[dst[e]], 1);
        jw[pos] = make_int2(s, __float_as_int(dinv[s]));
    }
}

// ---------------- weight transpose-casts (W1 and W2 in one launch) ----------------
__global__ void k_tcast2(const float* __restrict__ W1, ushort* __restrict__ w1t,
                         const float* __restrict__ W2, ushort* __restrict__ w2t) {
    int idx = blockIdx.x * 256 + threadIdx.x;
    const int n1 = F_IN * F_HID;
    if (idx < n1) {
        int n = idx / F_IN, k = idx - n * F_IN;
        w1t[idx] = f2bf(W1[(size_t)k * F_HID + n]);
    } else {
        int t = idx - n1;
        if (t < F_HID * F_OUT) {
            int n = t / F_HID, k = t - n * F_HID;
            w2t[t] = f2bf(W2[(size_t)k * F_OUT + n]);
        }
    }
}

// ---------------- GEMM1: h1[M,256] = bf16( fp32 x[M,512] @ w1t^T ) ----------------
// r13 structure (best measured): BM=64 x BN=128, 2x2 waves, double-buffered,
// B chunk-XOR swizzle, XCD pair-swizzle (FETCH-halving validated r13).
__global__ __launch_bounds__(256) void k_gemm1(
        const float* __restrict__ A, const ushort* __restrict__ Bt,
        ushort* __restrict__ C, int M, int nyblk) {
    constexpr int K = F_IN, Nc = F_HID, BM = 64, NT = K / 32;
    constexpr int ASTR = 36;
    __shared__ ushort As[2][BM * ASTR];
    __shared__ ushort Bs[2][128 * 32];
    const int tid  = threadIdx.x;
    const int wave = tid >> 6, lane = tid & 63;
    const int wr = wave & 1, wc = wave >> 1;

    // --- XCD pair-swizzle: L -> (bx, by) with pair members 8 apart ---
    int L = blockIdx.x;
    int nfull = (2 * nyblk) & ~15;
    int bx, by;
    if (L < nfull) {
        bx = (L >> 3) & 1;
        by = (L >> 4) * 8 + (L & 7);
    } else {
        int t = L - nfull;
        bx = t & 1;
        by = nfull / 2 + (t >> 1);
    }
    const int brow = by * BM, bcol = bx * 128;

    f32x4 acc[2][4];
    #pragma unroll
    for (int m = 0; m < 2; ++m)
        #pragma unroll
        for (int n = 0; n < 4; ++n) acc[m][n] = (f32x4){0.f, 0.f, 0.f, 0.f};

    const int arow = tid >> 2;
    const int akc  = (tid & 3) * 8;
    int agrow = brow + arow; if (agrow >= M) agrow = M - 1;
    const float4* ap = (const float4*)&A[(size_t)agrow * K + akc];
    const int csrc = (tid & 3) ^ ((tid >> 3) & 3);
    const ushort* bp0 = &Bt[(size_t)(bcol + (tid >> 2)) * K + csrc * 8];
    const ushort* bp1 = &Bt[(size_t)(bcol + 64 + (tid >> 2)) * K + csrc * 8];

    const int kqA = (lane >> 4) * 8;
    const int kqB = ((lane >> 4) ^ ((lane >> 1) & 3)) * 8;
    const int rA0 = wr * 32 + (lane & 15);
    const int rB0 = wc * 64 + (lane & 15);

    {
        float4 v0 = ap[0], v1 = ap[1];
        *(bf16x8*)&As[0][arow * ASTR + akc] = conv8(v0, v1);
        gload_lds16(bp0, &Bs[0][wave * 512]);
        gload_lds16(bp1, &Bs[0][2048 + wave * 512]);
    }
    __syncthreads();

    #pragma unroll
    for (int t = 0; t < NT; ++t) {
        const int b = t & 1;
        if (t + 1 < NT) {
            gload_lds16(bp0 + (t + 1) * 32, &Bs[b ^ 1][wave * 512]);
            gload_lds16(bp1 + (t + 1) * 32, &Bs[b ^ 1][2048 + wave * 512]);
            float4 v0 = ap[(t + 1) * 8], v1 = ap[(t + 1) * 8 + 1];
            *(bf16x8*)&As[b ^ 1][arow * ASTR + akc] = conv8(v0, v1);
        }
        bf16x8 af[2], bfr[4];
        #pragma unroll
        for (int m = 0; m < 2; ++m)
            af[m] = *(const bf16x8*)&As[b][(rA0 + m * 16) * ASTR + kqA];
        #pragma unroll
        for (int n = 0; n < 4; ++n)
            bfr[n] = *(const bf16x8*)&Bs[b][(rB0 + n * 16) * 32 + kqB];
        #pragma unroll
        for (int m = 0; m < 2; ++m)
            #pragma unroll
            for (int n = 0; n < 4; ++n)
                acc[m][n] = __builtin_amdgcn_mfma_f32_16x16x32_bf16(af[m], bfr[n], acc[m][n], 0, 0, 0);
        if (t + 1 < NT) __syncthreads();
    }

    const int crow0 = brow + wr * 32 + (lane >> 4) * 4;
    const int ccol0 = bcol + wc * 64 + (lane & 15);
    #pragma unroll
    for (int m = 0; m < 2; ++m)
        #pragma unroll
        for (int n = 0; n < 4; ++n)
            #pragma unroll
            for (int j = 0; j < 4; ++j) {
                int row = crow0 + m * 16 + j;
                if (row < M) C[(size_t)row * Nc + ccol0 + n * 16] = f2bf(acc[m][n][j]);
            }
}

// ---------------- bf16 MFMA GEMM2: C[M,Nc] = A[M,K] @ Bt[Nc,K]^T (bf16 out) ----------------
template<int WR, int WC, int MR, int NR>
__global__ __launch_bounds__(256) void k_gemm_bf16(
        const ushort* __restrict__ A, const ushort* __restrict__ Bt,
        ushort* __restrict__ C, int M, int K, int Nc) {
    constexpr int BM = WR * MR * 16;
    constexpr int BN = WC * NR * 16;
    __shared__ ushort As[BM * 32];
    __shared__ ushort Bs[BN * 32];
    const int tid  = threadIdx.x;
    const int wave = tid >> 6, lane = tid & 63;
    const int wr = wave % WR, wc = wave / WR;
    const int brow = blockIdx.y * BM, bcol = blockIdx.x * BN;

    f32x4 acc[MR][NR];
    #pragma unroll
    for (int m = 0; m < MR; ++m)
        #pragma unroll
        for (int n = 0; n < NR; ++n) acc[m][n] = (f32x4){0.f, 0.f, 0.f, 0.f};

    const int srow = tid >> 2;
    const int scol = (tid & 3) * 8;
    const int kq  = (lane >> 4) * 8;
    const int rA0 = wr * MR * 16 + (lane & 15);
    const int rB0 = wc * NR * 16 + (lane & 15);

    for (int k0 = 0; k0 < K; k0 += 32) {
        #pragma unroll
        for (int l = 0; l < BM / 64; ++l) {
            int row = brow + l * 64 + srow;
            if (row >= M) row = M - 1;
            gload_lds16(&A[(size_t)row * K + k0 + scol], &As[l * 2048 + wave * 512]);
        }
        #pragma unroll
        for (int l = 0; l < BN / 64; ++l) {
            int row = bcol + l * 64 + srow;
            gload_lds16(&Bt[(size_t)row * K + k0 + scol], &Bs[l * 2048 + wave * 512]);
        }
        __syncthreads();
        bf16x8 af[MR], bfr[NR];
        #pragma unroll
        for (int m = 0; m < MR; ++m)
            af[m] = *(const bf16x8*)&As[(rA0 + m * 16) * 32 + kq];
        #pragma unroll
        for (int n = 0; n < NR; ++n)
            bfr[n] = *(const bf16x8*)&Bs[(rB0 + n * 16) * 32 + kq];
        #pragma unroll
        for (int m = 0; m < MR; ++m)
            #pragma unroll
            for (int n = 0; n < NR; ++n)
                acc[m][n] = __builtin_amdgcn_mfma_f32_16x16x32_bf16(af[m], bfr[n], acc[m][n], 0, 0, 0);
        __syncthreads();
    }

    const int crow0 = brow + wr * MR * 16 + (lane >> 4) * 4;
    const int ccol0 = bcol + wc * NR * 16 + (lane & 15);
    #pragma unroll
    for (int m = 0; m < MR; ++m)
        #pragma unroll
        for (int n = 0; n < NR; ++n)
            #pragma unroll
            for (int j = 0; j < 4; ++j) {
                int row = crow0 + m * 16 + j;
                if (row < M) C[(size_t)row * Nc + ccol0 + n * 16] = f2bf(acc[m][n][j]);
            }
}

// ---------------- layer-1 aggregation: paired-row gathers, 16 edges/iter ----------------
__global__ __launch_bounds__(256) void k_agg1(
        const ushort* __restrict__ h, const int2* __restrict__ jw,
        const int* __restrict__ offs, const float* __restrict__ dinv,
        const float* __restrict__ bias, ushort* __restrict__ outm, int N) {
    int wave = threadIdx.x >> 6, lane = threadIdx.x & 63;
    int i = blockIdx.x * 4 + wave;
    if (i >= N) return;
    int g = lane & 31;        // features g*8 .. g*8+7
    int p = lane >> 5;        // edge parity
    float di = dinv[i];
    float acc[8];
    {
        bf16x8 hv = *(const bf16x8*)&h[(size_t)i * F_HID + g * 8];
        float w = (p == 0) ? di * di : 0.f;     // self loop counted once
        #pragma unroll
        for (int k = 0; k < 8; ++k) acc[k] = bf2f((ushort)hv[k]) * w;
    }
    int s = offs[i], e = offs[i + 1];
    for (int u = s; u < e; u += 16) {
        int2 a[8];
        #pragma unroll
        for (int q = 0; q < 8; ++q) a[q] = jw[u + 2 * q + p];   // overrun -> pad/next-node, masked
        bf16x8 hv[8];
        #pragma unroll
        for (int q = 0; q < 8; ++q)
            hv[q] = *(const bf16x8*)&h[(size_t)a[q].x * F_HID + g * 8];
        #pragma unroll
        for (int q = 0; q < 8; ++q) {
            float ww = (u + 2 * q + p < e) ? __int_as_float(a[q].y) * di : 0.f;
            #pragma unroll
            for (int k = 0; k < 8; ++k) acc[k] += bf2f((ushort)hv[q][k]) * ww;
        }
    }
    #pragma unroll
    for (int k = 0; k < 8; ++k) acc[k] += __shfl_xor(acc[k], 32, 64);
    if (p == 0) {
        float4 b0 = *(const float4*)&bias[g * 8];
        float4 b1 = *(const float4*)&bias[g * 8 + 4];
        bf16x8 o;
        o[0] = (short)f2bf(fmaxf(acc[0] + b0.x, 0.f));
        o[1] = (short)f2bf(fmaxf(acc[1] + b0.y, 0.f));
        o[2] = (short)f2bf(fmaxf(acc[2] + b0.z, 0.f));
        o[3] = (short)f2bf(fmaxf(acc[3] + b0.w, 0.f));
        o[4] = (short)f2bf(fmaxf(acc[4] + b1.x, 0.f));
        o[5] = (short)f2bf(fmaxf(acc[5] + b1.y, 0.f));
        o[6] = (short)f2bf(fmaxf(acc[6] + b1.z, 0.f));
        o[7] = (short)f2bf(fmaxf(acc[7] + b1.w, 0.f));
        *(bf16x8*)&outm[(size_t)i * F_HID + g * 8] = o;
    }
}

// ---------------- layer-2 aggregation + log_softmax: 4-parity paired gathers ----------------
// lane = (feature-quad g4 = lane&15 owning 4 features, parity p = lane>>4).
// One bf16x4 load covers 8B; lanes 0-15 of a parity read one full 128B row
// (coalesced). 8 loads/iter = 32 edges in flight. Symmetric shfl_xor reduces
// give every lane the parity-combined values, then row max/sum for softmax.
__global__ __launch_bounds__(256) void k_agg2(
        const ushort* __restrict__ h, const int2* __restrict__ jw,
        const int* __restrict__ offs, const float* __restrict__ dinv,
        const float* __restrict__ bias, float* __restrict__ outm, int N) {
    int wave = threadIdx.x >> 6, lane = threadIdx.x & 63;
    int i = blockIdx.x * 4 + wave;
    if (i >= N) return;
    int g4 = lane & 15;       // features g4*4 .. g4*4+3
    int p  = lane >> 4;       // edge parity 0..3
    float di = dinv[i];
    float acc[4];
    {
        bf16x4 hv = *(const bf16x4*)&h[(size_t)i * F_OUT + g4 * 4];
        float w = (p == 0) ? di * di : 0.f;     // self loop counted once
        #pragma unroll
        for (int k = 0; k < 4; ++k) acc[k] = bf2f((ushort)hv[k]) * w;
    }
    int s = offs[i], e = offs[i + 1];
    for (int u = s; u < e; u += 32) {
        int2 a[8];
        #pragma unroll
        for (int q = 0; q < 8; ++q) a[q] = jw[u + 4 * q + p];   // overrun -> pad, masked
        bf16x4 hv[8];
        #pragma unroll
        for (int q = 0; q < 8; ++q)
            hv[q] = *(const bf16x4*)&h[(size_t)a[q].x * F_OUT + g4 * 4];
        #pragma unroll
        for (int q = 0; q < 8; ++q) {
            float ww = (u + 4 * q + p < e) ? __int_as_float(a[q].y) * di : 0.f;
            #pragma unroll
            for (int k = 0; k < 4; ++k) acc[k] += bf2f((ushort)hv[q][k]) * ww;
        }
    }
    // combine the 4 parities (symmetric: all lanes get the full sum)
    #pragma unroll
    for (int k = 0; k < 4; ++k) {
        acc[k] += __shfl_xor(acc[k], 16, 64);
        acc[k] += __shfl_xor(acc[k], 32, 64);
    }
    float4 bv = *(const float4*)&bias[g4 * 4];
    acc[0] += bv.x; acc[1] += bv.y; acc[2] += bv.z; acc[3] += bv.w;
    // row max over 64 features (16 feature-quads, bits 0-3 of lane)
    float m = fmaxf(fmaxf(acc[0], acc[1]), fmaxf(acc[2], acc[3]));
    #pragma unroll
    for (int o = 8; o >= 1; o >>= 1) m = fmaxf(m, __shfl_xor(m, o, 64));
    float ssum = expf(acc[0] - m) + expf(acc[1] - m) + expf(acc[2] - m) + expf(acc[3] - m);
    #pragma unroll
    for (int o = 8; o >= 1; o >>= 1) ssum += __shfl_xor(ssum, o, 64);
    float lse = m + logf(ssum);
    if (p == 0) {
        float4 o4;
        o4.x = acc[0] - lse; o4.y = acc[1] - lse;
        o4.z = acc[2] - lse; o4.w = acc[3] - lse;
        *(float4*)&outm[(size_t)i * F_OUT + g4 * 4] = o4;
    }
}

extern "C" void kernel_launch(void* const* d_in, const int* in_sizes, int n_in,
                              void* d_out, int out_size, void* d_ws, size_t ws_size,
                              hipStream_t stream) {
    const float* x  = (const float*)d_in[0];
    const int*   ei = (const int*)d_in[1];
    const float* W1 = (const float*)d_in[2];
    const float* b1 = (const float*)d_in[3];
    const float* W2 = (const float*)d_in[4];
    const float* b2 = (const float*)d_in[5];
    float* out = (float*)d_out;

    int N = in_sizes[0] / F_IN;   // 50000
    int E = in_sizes[1] / 2;      // 800000
    const int* src = ei;
    const int* dst = ei + E;

    // workspace layout (16B aligned by construction)
    ushort* w1t = (ushort*)d_ws;                        // 256*512
    ushort* w2t = w1t + F_HID * F_IN;                   // 64*256
    ushort* h1  = w2t + F_OUT * F_HID;                  // N*256 bf16
    ushort* a1  = h1 + (size_t)N * F_HID;               // N*256 bf16
    int*    deg = (int*)(a1 + (size_t)N * F_HID);       // N
    float*  dinv = (float*)(deg + N);                   // N
    int*    offs = (int*)(dinv + N);                    // N+1
    int*    cursor = offs + N + 1;                      // N
    int*    bsums  = cursor + N;                        // 256
    int2*   jw = (int2*)(((uintptr_t)(bsums + 256) + 7) & ~(uintptr_t)7);  // E+32
    ushort* h2 = h1;     // alias: h1 dead after agg1

    int nch = (N + 255) / 256;

    hipMemsetAsync(deg, 0, sizeof(int) * N, stream);
    k_deg <<<(E + 255) / 256, 256, 0, stream>>>(dst, deg, E);
    k_scan1<<<nch, 256, 0, stream>>>(deg, offs, bsums, dinv, N);
    k_scan2<<<1, 256, 0, stream>>>(bsums, nch);
    k_scan3<<<nch, 256, 0, stream>>>(offs, bsums, cursor, jw, N, E);
    k_fill<<<(E + 255) / 256, 256, 0, stream>>>(src, dst, cursor, jw, dinv, E);

    // weight transpose-casts (one launch)
    int ntc = F_IN * F_HID + F_HID * F_OUT;
    k_tcast2<<<(ntc + 255) / 256, 256, 0, stream>>>(W1, w1t, W2, w2t);

    // layer 1: fused cast+GEMM (r13 structure + XCD pair-swizzle) + paired-16 aggregate
    int nyblk = (N + 63) / 64;
    k_gemm1<<<2 * nyblk, 256, 0, stream>>>(x, w1t, h1, N, nyblk);
    k_agg1<<<(N + 3) / 4, 256, 0, stream>>>(h1, jw, offs, dinv, b1, a1, N);

    // layer 2: GEMM (64x64 tile) + 4-parity aggregate + log_softmax
    k_gemm_bf16<4, 1, 1, 4><<<dim3(1, (N + 63) / 64), 256, 0, stream>>>(
        a1, w2t, h2, N, F_HID, F_OUT);
    k_agg2<<<(N + 3) / 4, 256, 0, stream>>>(h2, jw, offs, dinv, b2, out, N);
}

// Round 15
// 241.630 us; speedup vs baseline: 1.3400x; 1.0081x over previous
//
#include <hip/hip_runtime.h>
#include <math.h>

#define F_IN  512
#define F_HID 256
#define F_OUT 64

typedef __attribute__((ext_vector_type(8))) short bf16x8;
typedef __attribute__((ext_vector_type(4))) short bf16x4;
typedef __attribute__((ext_vector_type(4))) float f32x4;

#define GLOBAL_AS __attribute__((address_space(1)))
#define LDS_AS    __attribute__((address_space(3)))

__device__ __forceinline__ void gload_lds16(const void* g, void* l) {
    __builtin_amdgcn_global_load_lds((const GLOBAL_AS uint32_t*)g,
                                     (LDS_AS uint32_t*)l, 16, 0, 0);
}

__device__ __forceinline__ ushort f2bf(float f) {
    union { float f; uint32_t u; } v; v.f = f;
    uint32_t r = (v.u + 0x7FFFu + ((v.u >> 16) & 1u)) >> 16;
    return (ushort)r;
}

__device__ __forceinline__ float bf2f(ushort u) {
    union { uint32_t u; float f; } v; v.u = ((uint32_t)u) << 16;
    return v.f;
}

__device__ __forceinline__ bf16x8 conv8(float4 a, float4 b) {
    bf16x8 c;
    c[0] = (short)f2bf(a.x); c[1] = (short)f2bf(a.y);
    c[2] = (short)f2bf(a.z); c[3] = (short)f2bf(a.w);
    c[4] = (short)f2bf(b.x); c[5] = (short)f2bf(b.y);
    c[6] = (short)f2bf(b.z); c[7] = (short)f2bf(b.w);
    return c;
}

// ---------------- degree ----------------
__global__ void k_deg(const int* __restrict__ dst, int* __restrict__ deg, int E) {
    int e = blockIdx.x * 256 + threadIdx.x;
    if (e < E) atomicAdd(&deg[dst[e]], 1);
}

// ---------------- scan level 1 (+ dinv fused) ----------------
__global__ void k_scan1(const int* __restrict__ deg, int* __restrict__ offs,
                        int* __restrict__ bsums, float* __restrict__ dinv, int N) {
    __shared__ int s[256];
    int tid = threadIdx.x;
    int i = blockIdx.x * 256 + tid;
    int v = (i < N) ? deg[i] : 0;
    if (i < N) dinv[i] = rsqrtf((float)(v + 1));   // +1 self loop
    s[tid] = v; __syncthreads();
    for (int d = 1; d < 256; d <<= 1) {
        int t = (tid >= d) ? s[tid - d] : 0;
        __syncthreads();
        s[tid] += t;
        __syncthreads();
    }
    if (i < N) offs[i] = s[tid] - v;
    if (tid == 255) bsums[blockIdx.x] = s[255];
}

__global__ void k_scan2(int* __restrict__ bsums, int n) {
    __shared__ int s[256];
    int tid = threadIdx.x;
    int v = (tid < n) ? bsums[tid] : 0;
    s[tid] = v; __syncthreads();
    for (int d = 1; d < 256; d <<= 1) {
        int t = (tid >= d) ? s[tid - d] : 0;
        __syncthreads();
        s[tid] += t;
        __syncthreads();
    }
    if (tid < n) bsums[tid] = s[tid] - v;
}

__global__ void k_scan3(int* __restrict__ offs, const int* __restrict__ bsums,
                        int* __restrict__ cursor, int2* __restrict__ jw, int N, int E) {
    int i = blockIdx.x * 256 + threadIdx.x;
    if (i < N) {
        int o = offs[i] + bsums[i >> 8];
        offs[i] = o;
        cursor[i] = o;
    }
    if (i == 0) offs[N] = E;
    if (i < 32) jw[E + i] = make_int2(0, 0);   // pad: row 0, weight 0 (agg2 overruns <=31)
}

// fill packed (src_index, dinv[src]) per CSR slot
__global__ void k_fill(const int* __restrict__ src, const int* __restrict__ dst,
                       int* __restrict__ cursor, int2* __restrict__ jw,
                       const float* __restrict__ dinv, int E) {
    int e = blockIdx.x * 256 + threadIdx.x;
    if (e < E) {
        int s = src[e];
        int pos = atomicAdd(&cursor[dst[e]], 1);
        jw[pos] = make_int2(s, __float_as_int(dinv[s]));
    }
}

// ---------------- weight transpose-casts (W1 and W2 in one launch) ----------------
__global__ void k_tcast2(const float* __restrict__ W1, ushort* __restrict__ w1t,
                         const float* __restrict__ W2, ushort* __restrict__ w2t) {
    int idx = blockIdx.x * 256 + threadIdx.x;
    const int n1 = F_IN * F_HID;
    if (idx < n1) {
        int n = idx / F_IN, k = idx - n * F_IN;
        w1t[idx] = f2bf(W1[(size_t)k * F_HID + n]);
    } else {
        int t = idx - n1;
        if (t < F_HID * F_OUT) {
            int n = t / F_HID, k = t - n * F_HID;
            w2t[t] = f2bf(W2[(size_t)k * F_OUT + n]);
        }
    }
}

// ---------------- GEMM1: h1[M,256] = bf16( fp32 x[M,512] @ w1t^T ) ----------------
// BK=64 (8 iterations, half the barrier-drains of r13). BM=64 x BN=128, 2x2
// waves, double-buffered (51.2KB LDS -> 3 blocks/CU = grid 3.05/CU). B staged
// via 4 gload_lds/thread with 8-chunk XOR pre-swizzle c=(lane&7)^(lane>>3&7)
// (linear dest + inverse-swizzled source + swizzled read). XCD pair-swizzle.
__global__ __launch_bounds__(256) void k_gemm1(
        const float* __restrict__ A, const ushort* __restrict__ Bt,
        ushort* __restrict__ C, int M, int nyblk) {
    constexpr int K = F_IN, Nc = F_HID, BM = 64, NT = K / 64;   // 8 iterations
    constexpr int ASTR = 72;                                    // 64 + 8 pad (ushorts)
    __shared__ ushort As[2][BM * ASTR];     // 18.4 KB
    __shared__ ushort Bs[2][128 * 64];      // 32.0 KB
    const int tid  = threadIdx.x;
    const int wave = tid >> 6, lane = tid & 63;
    const int wr = wave & 1, wc = wave >> 1;
    const int l15 = lane & 15, hi = lane >> 4;

    // --- XCD pair-swizzle: pair members 8 linear ids apart (same XCD) ---
    int L = blockIdx.x;
    int nfull = (2 * nyblk) & ~15;
    int bx, by;
    if (L < nfull) { bx = (L >> 3) & 1; by = (L >> 4) * 8 + (L & 7); }
    else { int t = L - nfull; bx = t & 1; by = nfull / 2 + (t >> 1); }
    const int brow = by * BM, bcol = bx * 128;

    f32x4 acc[2][4];
    #pragma unroll
    for (int m = 0; m < 2; ++m)
        #pragma unroll
        for (int n = 0; n < 4; ++n) acc[m][n] = (f32x4){0.f, 0.f, 0.f, 0.f};

    // A stage: 4 thr/row, 16 fp32 (4x float4) each; iter t at ap[t*16 + q]
    const int arow = tid >> 2;
    const int akc  = (tid & 3) * 16;
    int agrow = brow + arow; if (agrow >= M) agrow = M - 1;
    const float4* ap = (const float4*)&A[(size_t)agrow * K + akc];
    // B stage: 4 instrs/thread; instr l covers rows (l*4+wave)*8 + (lane>>3),
    // phys chunk = lane&7, source logical chunk = (lane&7)^((lane>>3)&7).
    const int bc = (lane & 7) ^ ((lane >> 3) & 7);
    const ushort* bp[4];
    int bdst[4];
    #pragma unroll
    for (int l = 0; l < 4; ++l) {
        int g = l * 4 + wave;                  // instruction group 0..15
        int R = g * 8 + (lane >> 3);           // row 0..127
        bp[l]   = &Bt[(size_t)(bcol + R) * K + bc * 8];
        bdst[l] = g * 512;                     // ushort offset of 64-slot group
    }

    // ---- prologue: stage t=0 into buf 0 ----
    {
        float4 v0 = ap[0], v1 = ap[1], v2 = ap[2], v3 = ap[3];
        *(bf16x8*)&As[0][arow * ASTR + akc]     = conv8(v0, v1);
        *(bf16x8*)&As[0][arow * ASTR + akc + 8] = conv8(v2, v3);
        #pragma unroll
        for (int l = 0; l < 4; ++l) gload_lds16(bp[l], &Bs[0][bdst[l]]);
    }
    __syncthreads();

    #pragma unroll
    for (int t = 0; t < NT; ++t) {
        const int b = t & 1;
        if (t + 1 < NT) {
            #pragma unroll
            for (int l = 0; l < 4; ++l)
                gload_lds16(bp[l] + (t + 1) * 64, &Bs[b ^ 1][bdst[l]]);
            float4 v0 = ap[(t + 1) * 16], v1 = ap[(t + 1) * 16 + 1],
                   v2 = ap[(t + 1) * 16 + 2], v3 = ap[(t + 1) * 16 + 3];
            *(bf16x8*)&As[b ^ 1][arow * ASTR + akc]     = conv8(v0, v1);
            *(bf16x8*)&As[b ^ 1][arow * ASTR + akc + 8] = conv8(v2, v3);
        }
        // compute k-step t (two 32-wide MFMA substeps) from buf b
        #pragma unroll
        for (int ks = 0; ks < 2; ++ks) {
            const int kqA = ks * 32 + hi * 8;
            bf16x8 af[2], bfr[4];
            #pragma unroll
            for (int m = 0; m < 2; ++m)
                af[m] = *(const bf16x8*)&As[b][(wr * 32 + l15 + m * 16) * ASTR + kqA];
            #pragma unroll
            for (int n = 0; n < 4; ++n) {
                const int row = wc * 64 + l15 + n * 16;
                const int p = (ks * 4 + hi) ^ (l15 & 7);   // swizzled chunk
                bfr[n] = *(const bf16x8*)&Bs[b][row * 64 + p * 8];
            }
            #pragma unroll
            for (int m = 0; m < 2; ++m)
                #pragma unroll
                for (int n = 0; n < 4; ++n)
                    acc[m][n] = __builtin_amdgcn_mfma_f32_16x16x32_bf16(af[m], bfr[n], acc[m][n], 0, 0, 0);
        }
        if (t + 1 < NT) __syncthreads();
    }

    const int crow0 = brow + wr * 32 + hi * 4;
    const int ccol0 = bcol + wc * 64 + l15;
    #pragma unroll
    for (int m = 0; m < 2; ++m)
        #pragma unroll
        for (int n = 0; n < 4; ++n)
            #pragma unroll
            for (int j = 0; j < 4; ++j) {
                int row = crow0 + m * 16 + j;
                if (row < M) C[(size_t)row * Nc + ccol0 + n * 16] = f2bf(acc[m][n][j]);
            }
}

// ---------------- bf16 MFMA GEMM2: C[M,Nc] = A[M,K] @ Bt[Nc,K]^T (bf16 out) ----------------
template<int WR, int WC, int MR, int NR>
__global__ __launch_bounds__(256) void k_gemm_bf16(
        const ushort* __restrict__ A, const ushort* __restrict__ Bt,
        ushort* __restrict__ C, int M, int K, int Nc) {
    constexpr int BM = WR * MR * 16;
    constexpr int BN = WC * NR * 16;
    __shared__ ushort As[BM * 32];
    __shared__ ushort Bs[BN * 32];
    const int tid  = threadIdx.x;
    const int wave = tid >> 6, lane = tid & 63;
    const int wr = wave % WR, wc = wave / WR;
    const int brow = blockIdx.y * BM, bcol = blockIdx.x * BN;

    f32x4 acc[MR][NR];
    #pragma unroll
    for (int m = 0; m < MR; ++m)
        #pragma unroll
        for (int n = 0; n < NR; ++n) acc[m][n] = (f32x4){0.f, 0.f, 0.f, 0.f};

    const int srow = tid >> 2;
    const int scol = (tid & 3) * 8;
    const int kq  = (lane >> 4) * 8;
    const int rA0 = wr * MR * 16 + (lane & 15);
    const int rB0 = wc * NR * 16 + (lane & 15);

    for (int k0 = 0; k0 < K; k0 += 32) {
        #pragma unroll
        for (int l = 0; l < BM / 64; ++l) {
            int row = brow + l * 64 + srow;
            if (row >= M) row = M - 1;
            gload_lds16(&A[(size_t)row * K + k0 + scol], &As[l * 2048 + wave * 512]);
        }
        #pragma unroll
        for (int l = 0; l < BN / 64; ++l) {
            int row = bcol + l * 64 + srow;
            gload_lds16(&Bt[(size_t)row * K + k0 + scol], &Bs[l * 2048 + wave * 512]);
        }
        __syncthreads();
        bf16x8 af[MR], bfr[NR];
        #pragma unroll
        for (int m = 0; m < MR; ++m)
            af[m] = *(const bf16x8*)&As[(rA0 + m * 16) * 32 + kq];
        #pragma unroll
        for (int n = 0; n < NR; ++n)
            bfr[n] = *(const bf16x8*)&Bs[(rB0 + n * 16) * 32 + kq];
        #pragma unroll
        for (int m = 0; m < MR; ++m)
            #pragma unroll
            for (int n = 0; n < NR; ++n)
                acc[m][n] = __builtin_amdgcn_mfma_f32_16x16x32_bf16(af[m], bfr[n], acc[m][n], 0, 0, 0);
        __syncthreads();
    }

    const int crow0 = brow + wr * MR * 16 + (lane >> 4) * 4;
    const int ccol0 = bcol + wc * NR * 16 + (lane & 15);
    #pragma unroll
    for (int m = 0; m < MR; ++m)
        #pragma unroll
        for (int n = 0; n < NR; ++n)
            #pragma unroll
            for (int j = 0; j < 4; ++j) {
                int row = crow0 + m * 16 + j;
                if (row < M) C[(size_t)row * Nc + ccol0 + n * 16] = f2bf(acc[m][n][j]);
            }
}

// ---------------- layer-1 aggregation: paired-row gathers, 16 edges/iter ----------------
__global__ __launch_bounds__(256) void k_agg1(
        const ushort* __restrict__ h, const int2* __restrict__ jw,
        const int* __restrict__ offs, const float* __restrict__ dinv,
        const float* __restrict__ bias, ushort* __restrict__ outm, int N) {
    int wave = threadIdx.x >> 6, lane = threadIdx.x & 63;
    int i = blockIdx.x * 4 + wave;
    if (i >= N) return;
    int g = lane & 31;        // features g*8 .. g*8+7
    int p = lane >> 5;        // edge parity
    float di = dinv[i];
    float acc[8];
    {
        bf16x8 hv = *(const bf16x8*)&h[(size_t)i * F_HID + g * 8];
        float w = (p == 0) ? di * di : 0.f;     // self loop counted once
        #pragma unroll
        for (int k = 0; k < 8; ++k) acc[k] = bf2f((ushort)hv[k]) * w;
    }
    int s = offs[i], e = offs[i + 1];
    for (int u = s; u < e; u += 16) {
        int2 a[8];
        #pragma unroll
        for (int q = 0; q < 8; ++q) a[q] = jw[u + 2 * q + p];   // overrun -> pad/next-node, masked
        bf16x8 hv[8];
        #pragma unroll
        for (int q = 0; q < 8; ++q)
            hv[q] = *(const bf16x8*)&h[(size_t)a[q].x * F_HID + g * 8];
        #pragma unroll
        for (int q = 0; q < 8; ++q) {
            float ww = (u + 2 * q + p < e) ? __int_as_float(a[q].y) * di : 0.f;
            #pragma unroll
            for (int k = 0; k < 8; ++k) acc[k] += bf2f((ushort)hv[q][k]) * ww;
        }
    }
    #pragma unroll
    for (int k = 0; k < 8; ++k) acc[k] += __shfl_xor(acc[k], 32, 64);
    if (p == 0) {
        float4 b0 = *(const float4*)&bias[g * 8];
        float4 b1 = *(const float4*)&bias[g * 8 + 4];
        bf16x8 o;
        o[0] = (short)f2bf(fmaxf(acc[0] + b0.x, 0.f));
        o[1] = (short)f2bf(fmaxf(acc[1] + b0.y, 0.f));
        o[2] = (short)f2bf(fmaxf(acc[2] + b0.z, 0.f));
        o[3] = (short)f2bf(fmaxf(acc[3] + b0.w, 0.f));
        o[4] = (short)f2bf(fmaxf(acc[4] + b1.x, 0.f));
        o[5] = (short)f2bf(fmaxf(acc[5] + b1.y, 0.f));
        o[6] = (short)f2bf(fmaxf(acc[6] + b1.z, 0.f));
        o[7] = (short)f2bf(fmaxf(acc[7] + b1.w, 0.f));
        *(bf16x8*)&outm[(size_t)i * F_HID + g * 8] = o;
    }
}

// ---------------- layer-2 aggregation + log_softmax: 4-parity paired gathers ----------------
__global__ __launch_bounds__(256) void k_agg2(
        const ushort* __restrict__ h, const int2* __restrict__ jw,
        const int* __restrict__ offs, const float* __restrict__ dinv,
        const float* __restrict__ bias, float* __restrict__ outm, int N) {
    int wave = threadIdx.x >> 6, lane = threadIdx.x & 63;
    int i = blockIdx.x * 4 + wave;
    if (i >= N) return;
    int g4 = lane & 15;       // features g4*4 .. g4*4+3
    int p  = lane >> 4;       // edge parity 0..3
    float di = dinv[i];
    float acc[4];
    {
        bf16x4 hv = *(const bf16x4*)&h[(size_t)i * F_OUT + g4 * 4];
        float w = (p == 0) ? di * di : 0.f;     // self loop counted once
        #pragma unroll
        for (int k = 0; k < 4; ++k) acc[k] = bf2f((ushort)hv[k]) * w;
    }
    int s = offs[i], e = offs[i + 1];
    for (int u = s; u < e; u += 32) {
        int2 a[8];
        #pragma unroll
        for (int q = 0; q < 8; ++q) a[q] = jw[u + 4 * q + p];   // overrun -> pad, masked
        bf16x4 hv[8];
        #pragma unroll
        for (int q = 0; q < 8; ++q)
            hv[q] = *(const bf16x4*)&h[(size_t)a[q].x * F_OUT + g4 * 4];
        #pragma unroll
        for (int q = 0; q < 8; ++q) {
            float ww = (u + 4 * q + p < e) ? __int_as_float(a[q].y) * di : 0.f;
            #pragma unroll
            for (int k = 0; k < 4; ++k) acc[k] += bf2f((ushort)hv[q][k]) * ww;
        }
    }
    #pragma unroll
    for (int k = 0; k < 4; ++k) {
        acc[k] += __shfl_xor(acc[k], 16, 64);
        acc[k] += __shfl_xor(acc[k], 32, 64);
    }
    float4 bv = *(const float4*)&bias[g4 * 4];
    acc[0] += bv.x; acc[1] += bv.y; acc[2] += bv.z; acc[3] += bv.w;
    float m = fmaxf(fmaxf(acc[0], acc[1]), fmaxf(acc[2], acc[3]));
    #pragma unroll
    for (int o = 8; o >= 1; o >>= 1) m = fmaxf(m, __shfl_xor(m, o, 64));
    float ssum = expf(acc[0] - m) + expf(acc[1] - m) + expf(acc[2] - m) + expf(acc[3] - m);
    #pragma unroll
    for (int o = 8; o >= 1; o >>= 1) ssum += __shfl_xor(ssum, o, 64);
    float lse = m + logf(ssum);
    if (p == 0) {
        float4 o4;
        o4.x = acc[0] - lse; o4.y = acc[1] - lse;
        o4.z = acc[2] - lse; o4.w = acc[3] - lse;
        *(float4*)&outm[(size_t)i * F_OUT + g4 * 4] = o4;
    }
}

extern "C" void kernel_launch(void* const* d_in, const int* in_sizes, int n_in,
                              void* d_out, int out_size, void* d_ws, size_t ws_size,
                              hipStream_t stream) {
    const float* x  = (const float*)d_in[0];
    const int*   ei = (const int*)d_in[1];
    const float* W1 = (const float*)d_in[2];
    const float* b1 = (const float*)d_in[3];
    const float* W2 = (const float*)d_in[4];
    const float* b2 = (const float*)d_in[5];
    float* out = (float*)d_out;

    int N = in_sizes[0] / F_IN;   // 50000
    int E = in_sizes[1] / 2;      // 800000
    const int* src = ei;
    const int* dst = ei + E;

    // workspace layout (16B aligned by construction)
    ushort* w1t = (ushort*)d_ws;                        // 256*512
    ushort* w2t = w1t + F_HID * F_IN;                   // 64*256
    ushort* h1  = w2t + F_OUT * F_HID;                  // N*256 bf16
    ushort* a1  = h1 + (size_t)N * F_HID;               // N*256 bf16
    int*    deg = (int*)(a1 + (size_t)N * F_HID);       // N
    float*  dinv = (float*)(deg + N);                   // N
    int*    offs = (int*)(dinv + N);                    // N+1
    int*    cursor = offs + N + 1;                      // N
    int*    bsums  = cursor + N;                        // 256
    int2*   jw = (int2*)(((uintptr_t)(bsums + 256) + 7) & ~(uintptr_t)7);  // E+32
    ushort* h2 = h1;     // alias: h1 dead after agg1

    int nch = (N + 255) / 256;

    hipMemsetAsync(deg, 0, sizeof(int) * N, stream);
    k_deg <<<(E + 255) / 256, 256, 0, stream>>>(dst, deg, E);
    k_scan1<<<nch, 256, 0, stream>>>(deg, offs, bsums, dinv, N);
    k_scan2<<<1, 256, 0, stream>>>(bsums, nch);
    k_scan3<<<nch, 256, 0, stream>>>(offs, bsums, cursor, jw, N, E);
    k_fill<<<(E + 255) / 256, 256, 0, stream>>>(src, dst, cursor, jw, dinv, E);

    // weight transpose-casts (one launch)
    int ntc = F_IN * F_HID + F_HID * F_OUT;
    k_tcast2<<<(ntc + 255) / 256, 256, 0, stream>>>(W1, w1t, W2, w2t);

    // layer 1: fused cast+GEMM (BK=64, 8 barriers) + paired-16 aggregate
    int nyblk = (N + 63) / 64;
    k_gemm1<<<2 * nyblk, 256, 0, stream>>>(x, w1t, h1, N, nyblk);
    k_agg1<<<(N + 3) / 4, 256, 0, stream>>>(h1, jw, offs, dinv, b1, a1, N);

    // layer 2: GEMM (64x64 tile) + 4-parity aggregate + log_softmax
    k_gemm_bf16<4, 1, 1, 4><<<dim3(1, (N + 63) / 64), 256, 0, stream>>>(
        a1, w2t, h2, N, F_HID, F_OUT);
    k_agg2<<<(N + 3) / 4, 256, 0, stream>>>(h2, jw, offs, dinv, b2, out, N);
}